// Round 4
// baseline (296.101 us; speedup 1.0000x reference)
//
#include <hip/hip_runtime.h>
#include <hip/hip_bf16.h>
#include <stdint.h>

#define BB 4
#define NN 1024
#define DD 1024
#define HH 16
#define HDIM 64
#define KVHH 4
#define MM (BB * NN)  // 4096 token rows

typedef __hip_bfloat16 bf16;
typedef __attribute__((ext_vector_type(8))) short bf16x8;  // 8 bf16 = 4 VGPR
typedef __attribute__((ext_vector_type(4))) short bf16x4;  // 4 bf16 = 2 VGPR
typedef __attribute__((ext_vector_type(4))) float f32x4;

__device__ __forceinline__ float b2f(unsigned short u) {
  return __uint_as_float(((unsigned)u) << 16);
}
__device__ __forceinline__ unsigned short f2b(float x) {
  bf16 h = __float2bfloat16(x);
  unsigned short u;
  __builtin_memcpy(&u, &h, 2);
  return u;
}
__device__ __forceinline__ f32x4 mfma16(bf16x8 a, bf16x8 b, f32x4 c) {
  return __builtin_amdgcn_mfma_f32_16x16x32_bf16(a, b, c, 0, 0, 0);
}
// K=16 MFMA: B-fragment layout (col=l15, k=quad*4+i) matches the K=32 MFMA's
// C layout (col=l15, row=quad*4+r) -> S output feeds PV directly, in-register.
// (Correctness of this mapping HW-verified in r12/r13: absmax matched r11.)
__device__ __forceinline__ f32x4 mfma16k16(bf16x4 a, bf16x4 b, f32x4 c) {
#if __has_builtin(__builtin_amdgcn_mfma_f32_16x16x16bf16_1k)
  return __builtin_amdgcn_mfma_f32_16x16x16bf16_1k(a, b, c, 0, 0, 0);
#else
  asm("s_nop 1\n\tv_mfma_f32_16x16x16_bf16 %0, %1, %2, %0"
      : "+v"(c)
      : "v"(a), "v"(b));
  return c;
#endif
}
__device__ __forceinline__ void gl_lds16(const short* g, short* l) {
  __builtin_amdgcn_global_load_lds(
      (const __attribute__((address_space(1))) unsigned*)g,
      (__attribute__((address_space(3))) unsigned*)l, 16, 0, 0);
}

// ---------------------------------------------------------------------------
// z=0..3: weight transposes W (K x N fp32) -> WT (N x K bf16), 64x64 tiles.
// z=4: combined bias build. z=5: x fp32 -> bf16 convert.
// ---------------------------------------------------------------------------
__global__ __launch_bounds__(256) void transpose_all(
    const float* __restrict__ Wq, const float* __restrict__ Wkv,
    const float* __restrict__ Wg, const float* __restrict__ Wo,
    const float* __restrict__ bg, const float* __restrict__ x,
    short* __restrict__ WcT, short* __restrict__ WoT,
    float* __restrict__ bias, short* __restrict__ xb) {
  const int z = blockIdx.z;
  if (z == 4) {  // combined bias: [0,1024)=0, [1024,2048)=bg, [2048,2560)=0
    if (blockIdx.y == 0 && blockIdx.x < 10) {
      int i = blockIdx.x * 256 + threadIdx.x;
      if (i < 2560) bias[i] = (i >= 1024 && i < 2048) ? bg[i - 1024] : 0.f;
    }
    return;
  }
  if (z == 5) {  // x convert: 256 blocks x 256 threads x 16 float4
    int base = (blockIdx.y * 16 + blockIdx.x) * 256 + threadIdx.x;
#pragma unroll
    for (int it = 0; it < 16; ++it) {
      int i = base + it * 65536;
      float4 v = *(const float4*)&x[(size_t)i * 4];
      ushort4 o;
      o.x = f2b(v.x); o.y = f2b(v.y); o.z = f2b(v.z); o.w = f2b(v.w);
      *(ushort4*)&xb[(size_t)i * 4] = o;
    }
    return;
  }
  const float* W;
  short* WT;
  int N = 1024;
  const int K = 1024;
  if (z == 0) { W = Wq; WT = WcT; }
  else if (z == 1) { W = Wg; WT = WcT + 1048576; }
  else if (z == 2) {
    W = Wkv; WT = WcT + 2097152; N = 512;
    if (blockIdx.x >= 8) return;  // uniform early-out, before any sync
  } else { W = Wo; WT = WoT; }

  __shared__ short T[64 * 68];
  const int tid = threadIdx.x;
  const int n0 = blockIdx.x * 64, k0 = blockIdx.y * 64;
  {
    int i0 = tid >> 4, j4 = (tid & 15) * 4;
#pragma unroll
    for (int ii = 0; ii < 4; ++ii) {
      int i = i0 + 16 * ii;
      float4 w = *(const float4*)&W[(size_t)(k0 + i) * N + n0 + j4];
      ushort4 o;
      o.x = f2b(w.x); o.y = f2b(w.y); o.z = f2b(w.z); o.w = f2b(w.w);
      *(ushort4*)&T[i * 68 + j4] = o;
    }
  }
  __syncthreads();
  {
    int n = tid >> 2, k16 = (tid & 3) * 16;
    short tmp[16];
#pragma unroll
    for (int kk = 0; kk < 16; ++kk) tmp[kk] = T[(k16 + kk) * 68 + n];
    short* dst = WT + (size_t)(n0 + n) * K + k0 + k16;
#pragma unroll
    for (int s = 0; s < 16; s += 4) *(ushort4*)&dst[s] = *(const ushort4*)&tmp[s];
  }
}

// ---------------------------------------------------------------------------
// Fused projection GEMM: 64x128 tile (grid 20x64 = 1280 blocks = 5/CU), BK=32,
// double-buffered gl_lds. Epilogue diverts to compact head-major buffers.
// NEW: q-head outputs are pre-scaled by log2e/8 so attention's softmax is a
// bare exp2 (folds the scale multiply out of the attn inner loop).
// ---------------------------------------------------------------------------
__global__ __launch_bounds__(256, 5) void gemm_proj(
    const short* __restrict__ A, const short* __restrict__ WT,
    const float* __restrict__ bias, short* __restrict__ qc,
    short* __restrict__ gc, short* __restrict__ kc, short* __restrict__ vt) {
  __shared__ short As[2][64 * 32];
  __shared__ short Bs[2][128 * 32];
  const int tid = threadIdx.x;
  const int wave = tid >> 6, lane = tid & 63, l15 = lane & 15, quad = lane >> 4;
  const int m0 = blockIdx.y * 64, n0 = blockIdx.x * 128;
  const int wm = (wave & 1) * 32, wn = (wave >> 1) * 64;
  const int arow = tid >> 2, ac = (tid & 3) * 8;
  const short* asrc = A + (size_t)(m0 + arow) * 1024 + ac;
  const short* bsrc = WT + (size_t)(n0 + arow) * 1024 + ac;

  gl_lds16(asrc, &As[0][wave * 512]);
  gl_lds16(bsrc, &Bs[0][wave * 512]);
  gl_lds16(bsrc + 64 * 1024, &Bs[0][wave * 512 + 2048]);

  f32x4 acc[2][4] = {};
  for (int k = 0; k < 32; ++k) {
    const int cur = k & 1;
    __syncthreads();  // stage(k) landed; iter k-1 LDS reads drained
    if (k < 31) {
      const short* ap = asrc + (k + 1) * 32;
      const short* bp = bsrc + (k + 1) * 32;
      gl_lds16(ap, &As[1 - cur][wave * 512]);
      gl_lds16(bp, &Bs[1 - cur][wave * 512]);
      gl_lds16(bp + 64 * 1024, &Bs[1 - cur][wave * 512 + 2048]);
    }
    bf16x8 af[2], bfr[4];
#pragma unroll
    for (int i = 0; i < 2; ++i)
      af[i] = *(const bf16x8*)&As[cur][(wm + 16 * i + l15) * 32 + quad * 8];
#pragma unroll
    for (int j = 0; j < 4; ++j)
      bfr[j] = *(const bf16x8*)&Bs[cur][(wn + 16 * j + l15) * 32 + quad * 8];
#pragma unroll
    for (int i = 0; i < 2; ++i)
#pragma unroll
      for (int j = 0; j < 4; ++j) acc[i][j] = mfma16(af[i], bfr[j], acc[i][j]);
  }
#pragma unroll
  for (int j = 0; j < 4; ++j) {
    int col = n0 + wn + 16 * j + l15;
    float bv = bias[col];
    int reg = col >> 6;  // head-slot 0..39 (uniform across the 16 lanes)
    int d = col & 63;
#pragma unroll
    for (int i = 0; i < 2; ++i) {
#pragma unroll
      for (int r = 0; r < 4; ++r) {
        int row = m0 + wm + 16 * i + quad * 4 + r;
        int b = row >> 10, tok = row & 1023;
        if (reg < 16) {  // q: pre-scale by 0.125*log2e (softmax fold)
          unsigned short v = f2b(acc[i][j][r] * 0.18033688f);
          ((unsigned short*)qc)[((size_t)((b * 16 + reg) * 1024 + tok)) * 64 + d] = v;
        } else {
          unsigned short v = f2b(acc[i][j][r] + bv);
          if (reg < 32)
            ((unsigned short*)gc)[((size_t)((b * 16 + reg - 16) * 1024 + tok)) * 64 + d] = v;
          else if (reg < 36)
            ((unsigned short*)kc)[((size_t)((b * 4 + reg - 32) * 1024 + tok)) * 64 + d] = v;
          else
            ((unsigned short*)vt)[((size_t)((b * 4 + reg - 36) * 64 + d)) * 1024 + tok] = v;
        }
      }
    }
  }
}

// ---------------------------------------------------------------------------
// Output-projection GEMM (r7-proven): 64x64 tile, grid 16x64 = 1024 blocks,
// BK=32, double-buffered gl_lds, 4 waves = 2x2 of (32m x 32n).
// ---------------------------------------------------------------------------
__global__ __launch_bounds__(256, 4) void gemm_out(
    const short* __restrict__ A, const short* __restrict__ WT,
    float* __restrict__ Cout) {
  __shared__ short As[2][64 * 32];
  __shared__ short Bs[2][64 * 32];
  const int tid = threadIdx.x;
  const int wave = tid >> 6, lane = tid & 63, l15 = lane & 15, quad = lane >> 4;
  const int m0 = blockIdx.y * 64, n0 = blockIdx.x * 64;
  const int wm = (wave & 1) * 32, wn = (wave >> 1) * 32;
  const int arow = tid >> 2, ac = (tid & 3) * 8;
  const short* asrc = A + (size_t)(m0 + arow) * 1024 + ac;
  const short* bsrc = WT + (size_t)(n0 + arow) * 1024 + ac;

  gl_lds16(asrc, &As[0][wave * 512]);
  gl_lds16(bsrc, &Bs[0][wave * 512]);

  f32x4 acc[2][2] = {};
  for (int k = 0; k < 32; ++k) {
    const int cur = k & 1;
    __syncthreads();
    if (k < 31) {
      gl_lds16(asrc + (k + 1) * 32, &As[1 - cur][wave * 512]);
      gl_lds16(bsrc + (k + 1) * 32, &Bs[1 - cur][wave * 512]);
    }
    bf16x8 af[2], bfr[2];
#pragma unroll
    for (int i = 0; i < 2; ++i)
      af[i] = *(const bf16x8*)&As[cur][(wm + 16 * i + l15) * 32 + quad * 8];
#pragma unroll
    for (int j = 0; j < 2; ++j)
      bfr[j] = *(const bf16x8*)&Bs[cur][(wn + 16 * j + l15) * 32 + quad * 8];
#pragma unroll
    for (int i = 0; i < 2; ++i)
#pragma unroll
      for (int j = 0; j < 2; ++j) acc[i][j] = mfma16(af[i], bfr[j], acc[i][j]);
  }
#pragma unroll
  for (int j = 0; j < 2; ++j) {
    int col = n0 + wn + 16 * j + l15;
#pragma unroll
    for (int i = 0; i < 2; ++i) {
#pragma unroll
      for (int r = 0; r < 4; ++r) {
        int row = m0 + wm + 16 * i + quad * 4 + r;
        Cout[(size_t)row * 1024 + col] = acc[i][j][r];
      }
    }
  }
}

// ---------------------------------------------------------------------------
// MFMA flash attention + gate, round 14: barrier-free main loop, SINGLE-
// buffered K/V (r12/r13 post-mortem: oacc64+qf32+double-buffers blew the
// 128-VGPR budget -> 140MB scratch spill at VGPR=84). Register budget by
// construction: oacc 64 + qf 32 + K 8 + V 8 + temps ~14 = ~118 < 128 cap
// (__launch_bounds__(256,4): 4 blocks/CU, LDS 4x34.5KB=138KB fits 160KB).
// K/V loads are L2-hot (~200cyc); 16 waves/CU TLP hides them. S output
// (col=l15=q, row=4quad+r=key) IS the K=16 MFMA B-frag layout, so P feeds
// PV directly in-register: zero barriers in main loop. qc is pre-scaled by
// log2e/8, so softmax is a bare exp2. Cross-wave O reduction at end.
// ---------------------------------------------------------------------------
__global__ __launch_bounds__(256, 4) void attn_mfma11(
    const short* __restrict__ qc, const short* __restrict__ gc,
    const short* __restrict__ kc, const short* __restrict__ vt,
    unsigned short* __restrict__ gated) {
  __shared__ float OA[64 * 65];
  __shared__ float OB[64 * 65];
  __shared__ float Lpart[4 * 64];
  __shared__ float Lq[64];
  const int tid = threadIdx.x;
  const int w = tid >> 6, lane = tid & 63, l15 = lane & 15, quad = lane >> 4;
  const int qt = blockIdx.x, bh = blockIdx.y, b = bh >> 4, h = bh & 15, kvh = h >> 2;

  // Q B-frags (loop-invariant): col q = qt*64+16jq+l15, k = d = quad*8+i (+32)
  bf16x8 qf[4][2];
#pragma unroll
  for (int jq = 0; jq < 4; ++jq) {
    const short* qp =
        qc + ((size_t)((b * 16 + h) * 1024) + qt * 64 + 16 * jq + l15) * 64 + quad * 8;
    qf[jq][0] = *(const bf16x8*)qp;
    qf[jq][1] = *(const bf16x8*)(qp + 32);
  }

  // K A-frag base: row key = kt*64 + 16w + l15 of kc[b,kvh,tok,64]; k = d
  const short* kbase =
      kc + ((size_t)((b * 4 + kvh) * 1024) + 16 * w + l15) * 64 + quad * 8;
  // V A-frag base: row d = dt*16 + l15 of vt[b,kvh,d,tok]; k = key = 4quad+i
  const short* vbase =
      vt + ((size_t)((b * 4 + kvh) * 64 + l15)) * 1024 + 16 * w + quad * 4;

  f32x4 oacc[4][4] = {};  // [jq][dt]: O^T partial, d = 16dt+4quad+r, q = 16jq+l15
  float ls[4] = {0.f, 0.f, 0.f, 0.f};

  for (int kt = 0; kt < 16; ++kt) {
    const short* kp = kbase + (size_t)kt * 4096;
    const short* vp = vbase + kt * 64;
    bf16x8 k0 = *(const bf16x8*)(kp);
    bf16x8 k1 = *(const bf16x8*)(kp + 32);
    bf16x4 v0 = *(const bf16x4*)(vp);
    bf16x4 v1 = *(const bf16x4*)(vp + 16384);
    bf16x4 v2 = *(const bf16x4*)(vp + 32768);
    bf16x4 v3 = *(const bf16x4*)(vp + 49152);
#pragma unroll
    for (int jq = 0; jq < 4; ++jq) {
      // S^T = K·Q^T: C col = l15 = q, row = 4quad+r = key_local
      f32x4 st = mfma16(k0, qf[jq][0], (f32x4){0.f, 0.f, 0.f, 0.f});
      st = mfma16(k1, qf[jq][1], st);
      float p0 = exp2f(st[0]);  // scale pre-folded into qc
      float p1 = exp2f(st[1]);
      float p2 = exp2f(st[2]);
      float p3 = exp2f(st[3]);
      ls[jq] += (p0 + p1) + (p2 + p3);
      bf16x4 pbf;
      pbf[0] = (short)f2b(p0);
      pbf[1] = (short)f2b(p1);
      pbf[2] = (short)f2b(p2);
      pbf[3] = (short)f2b(p3);
      // PV: O^T[d][q] += V^T[d][key] · P^T[key][q], k = 16 keys of this wave
      oacc[jq][0] = mfma16k16(v0, pbf, oacc[jq][0]);
      oacc[jq][1] = mfma16k16(v1, pbf, oacc[jq][1]);
      oacc[jq][2] = mfma16k16(v2, pbf, oacc[jq][2]);
      oacc[jq][3] = mfma16k16(v3, pbf, oacc[jq][3]);
    }
  }

  // l reduction: quad-reduce in-wave (sum over this wave's keys per q)
#pragma unroll
  for (int jq = 0; jq < 4; ++jq) {
    ls[jq] += __shfl_xor(ls[jq], 16);
    ls[jq] += __shfl_xor(ls[jq], 32);
  }
  if (quad == 0) {
#pragma unroll
    for (int jq = 0; jq < 4; ++jq) Lpart[w * 64 + 16 * jq + l15] = ls[jq];
  }

  // cross-wave O reduction: w0 writes OA, w1 writes OB; then w2 adds OA,
  // w3 adds OB; epilogue reads OA+OB.
  float* Ob = (w & 1) ? OB : OA;
  if (w < 2) {
#pragma unroll
    for (int jq = 0; jq < 4; ++jq)
#pragma unroll
      for (int dt = 0; dt < 4; ++dt)
#pragma unroll
        for (int r = 0; r < 4; ++r)
          Ob[(16 * dt + 4 * quad + r) * 65 + 16 * jq + l15] = oacc[jq][dt][r];
  }
  __syncthreads();
  if (w >= 2) {
#pragma unroll
    for (int jq = 0; jq < 4; ++jq)
#pragma unroll
      for (int dt = 0; dt < 4; ++dt)
#pragma unroll
        for (int r = 0; r < 4; ++r)
          Ob[(16 * dt + 4 * quad + r) * 65 + 16 * jq + l15] += oacc[jq][dt][r];
  }
  if (tid < 64)
    Lq[tid] = Lpart[tid] + Lpart[64 + tid] + Lpart[128 + tid] + Lpart[192 + tid];
  __syncthreads();

  // epilogue: O rows q = 16jq+4quad+r, cols d = 16w+l15; gate + store
  const int d = 16 * w + l15;
#pragma unroll
  for (int jq = 0; jq < 4; ++jq) {
#pragma unroll
    for (int r = 0; r < 4; ++r) {
      int qloc = 16 * jq + 4 * quad + r;
      float ov = OA[d * 65 + qloc] + OB[d * 65 + qloc];
      float lv = Lq[qloc];
      float gv = b2f(((const unsigned short*)gc)[
          ((size_t)((b * 16 + h) * 1024) + qt * 64 + qloc) * 64 + d]);
      size_t row = (size_t)(b * NN + qt * 64 + qloc);
      gated[row * 1024 + h * 64 + d] = f2b(ov / lv * gv);
    }
  }
}

// ---------------------------------------------------------------------------
extern "C" void kernel_launch(void* const* d_in, const int* in_sizes, int n_in,
                              void* d_out, int out_size, void* d_ws,
                              size_t ws_size, hipStream_t stream) {
  const float* x = (const float*)d_in[0];
  const float* Wq = (const float*)d_in[1];
  const float* Wkv = (const float*)d_in[2];
  const float* Wg = (const float*)d_in[3];
  const float* bg = (const float*)d_in[4];
  const float* Wo = (const float*)d_in[5];
  float* out = (float*)d_out;

  // ws layout (short elems): ~36.6 MB total
  short* ws = (short*)d_ws;
  short* xb = ws;                     // 4.19M (x bf16; later aliased as gated)
  short* WcT = xb + 4194304;          // 2.62M (W^T combined: q|g|kv rows)
  short* WoT = WcT + 2621440;         // 1.05M
  short* qc = WoT + 1048576;          // 4.19M  q[b,h,tok,d]
  short* gc = qc + 4194304;           // 4.19M  gate[b,h,tok,d]
  short* kc = gc + 4194304;           // 1.05M  k[b,kvh,tok,d]
  short* vtw = kc + 1048576;          // 1.05M  v^T[b,kvh,d,tok]
  float* bias_f32 = (float*)(vtw + 1048576);  // 2560 f32

  dim3 blk(256);
  // weight transposes + bias + x-convert, one dispatch
  transpose_all<<<dim3(16, 16, 6), blk, 0, stream>>>(Wq, Wkv, Wg, Wo, bg, x,
                                                     WcT, WoT, bias_f32, xb);
  // fused q|gate|kv projection (outputs diverted to compact layouts)
  gemm_proj<<<dim3(20, 64), blk, 0, stream>>>(xb, WcT, bias_f32, qc, gc, kc, vtw);
  // attention + gate -> gated (aliases xb; xb no longer needed)
  attn_mfma11<<<dim3(16, 64), blk, 0, stream>>>(qc, gc, kc, vtw, (unsigned short*)xb);
  // output projection
  gemm_out<<<dim3(16, 64), blk, 0, stream>>>(xb, WoT, out);
}

// Round 5
// 240.035 us; speedup vs baseline: 1.2336x; 1.2336x over previous
//
#include <hip/hip_runtime.h>
#include <hip/hip_bf16.h>
#include <stdint.h>

#define BB 4
#define NN 1024
#define DD 1024
#define HH 16
#define HDIM 64
#define KVHH 4
#define MM (BB * NN)  // 4096 token rows

typedef __hip_bfloat16 bf16;
typedef __attribute__((ext_vector_type(8))) short bf16x8;  // 8 bf16 = 4 VGPR
typedef __attribute__((ext_vector_type(4))) short bf16x4;  // 4 bf16 = 2 VGPR
typedef __attribute__((ext_vector_type(4))) float f32x4;

__device__ __forceinline__ float b2f(unsigned short u) {
  return __uint_as_float(((unsigned)u) << 16);
}
__device__ __forceinline__ unsigned short f2b(float x) {
  bf16 h = __float2bfloat16(x);
  unsigned short u;
  __builtin_memcpy(&u, &h, 2);
  return u;
}
__device__ __forceinline__ f32x4 mfma16(bf16x8 a, bf16x8 b, f32x4 c) {
  return __builtin_amdgcn_mfma_f32_16x16x32_bf16(a, b, c, 0, 0, 0);
}
// K=16 MFMA: B-fragment layout (col=l15, k=quad*4+i) matches the K=32 MFMA's
// C layout (col=l15, row=quad*4+r) -> S output feeds PV directly, in-register.
// (Correctness of this mapping HW-verified in r12-r14: absmax identical.)
__device__ __forceinline__ f32x4 mfma16k16(bf16x4 a, bf16x4 b, f32x4 c) {
#if __has_builtin(__builtin_amdgcn_mfma_f32_16x16x16bf16_1k)
  return __builtin_amdgcn_mfma_f32_16x16x16bf16_1k(a, b, c, 0, 0, 0);
#else
  asm("s_nop 1\n\tv_mfma_f32_16x16x16_bf16 %0, %1, %2, %0"
      : "+v"(c)
      : "v"(a), "v"(b));
  return c;
#endif
}
__device__ __forceinline__ void gl_lds16(const short* g, short* l) {
  __builtin_amdgcn_global_load_lds(
      (const __attribute__((address_space(1))) unsigned*)g,
      (__attribute__((address_space(3))) unsigned*)l, 16, 0, 0);
}

// ---------------------------------------------------------------------------
// z=0..3: weight transposes W (K x N fp32) -> WT (N x K bf16), 64x64 tiles.
// z=4: combined bias build. z=5: x fp32 -> bf16 convert.
// ---------------------------------------------------------------------------
__global__ __launch_bounds__(256) void transpose_all(
    const float* __restrict__ Wq, const float* __restrict__ Wkv,
    const float* __restrict__ Wg, const float* __restrict__ Wo,
    const float* __restrict__ bg, const float* __restrict__ x,
    short* __restrict__ WcT, short* __restrict__ WoT,
    float* __restrict__ bias, short* __restrict__ xb) {
  const int z = blockIdx.z;
  if (z == 4) {  // combined bias: [0,1024)=0, [1024,2048)=bg, [2048,2560)=0
    if (blockIdx.y == 0 && blockIdx.x < 10) {
      int i = blockIdx.x * 256 + threadIdx.x;
      if (i < 2560) bias[i] = (i >= 1024 && i < 2048) ? bg[i - 1024] : 0.f;
    }
    return;
  }
  if (z == 5) {  // x convert: 256 blocks x 256 threads x 16 float4
    int base = (blockIdx.y * 16 + blockIdx.x) * 256 + threadIdx.x;
#pragma unroll
    for (int it = 0; it < 16; ++it) {
      int i = base + it * 65536;
      float4 v = *(const float4*)&x[(size_t)i * 4];
      ushort4 o;
      o.x = f2b(v.x); o.y = f2b(v.y); o.z = f2b(v.z); o.w = f2b(v.w);
      *(ushort4*)&xb[(size_t)i * 4] = o;
    }
    return;
  }
  const float* W;
  short* WT;
  int N = 1024;
  const int K = 1024;
  if (z == 0) { W = Wq; WT = WcT; }
  else if (z == 1) { W = Wg; WT = WcT + 1048576; }
  else if (z == 2) {
    W = Wkv; WT = WcT + 2097152; N = 512;
    if (blockIdx.x >= 8) return;  // uniform early-out, before any sync
  } else { W = Wo; WT = WoT; }

  __shared__ short T[64 * 68];
  const int tid = threadIdx.x;
  const int n0 = blockIdx.x * 64, k0 = blockIdx.y * 64;
  {
    int i0 = tid >> 4, j4 = (tid & 15) * 4;
#pragma unroll
    for (int ii = 0; ii < 4; ++ii) {
      int i = i0 + 16 * ii;
      float4 w = *(const float4*)&W[(size_t)(k0 + i) * N + n0 + j4];
      ushort4 o;
      o.x = f2b(w.x); o.y = f2b(w.y); o.z = f2b(w.z); o.w = f2b(w.w);
      *(ushort4*)&T[i * 68 + j4] = o;
    }
  }
  __syncthreads();
  {
    int n = tid >> 2, k16 = (tid & 3) * 16;
    short tmp[16];
#pragma unroll
    for (int kk = 0; kk < 16; ++kk) tmp[kk] = T[(k16 + kk) * 68 + n];
    short* dst = WT + (size_t)(n0 + n) * K + k0 + k16;
#pragma unroll
    for (int s = 0; s < 16; s += 4) *(ushort4*)&dst[s] = *(const ushort4*)&tmp[s];
  }
}

// ---------------------------------------------------------------------------
// Fused projection GEMM: 64x128 tile (grid 20x64 = 1280 blocks = 5/CU), BK=32,
// double-buffered gl_lds. Epilogue diverts to compact head-major buffers.
// q-head outputs are pre-scaled by log2e/8 so attention's softmax is bare exp2.
// ---------------------------------------------------------------------------
__global__ __launch_bounds__(256, 5) void gemm_proj(
    const short* __restrict__ A, const short* __restrict__ WT,
    const float* __restrict__ bias, short* __restrict__ qc,
    short* __restrict__ gc, short* __restrict__ kc, short* __restrict__ vt) {
  __shared__ short As[2][64 * 32];
  __shared__ short Bs[2][128 * 32];
  const int tid = threadIdx.x;
  const int wave = tid >> 6, lane = tid & 63, l15 = lane & 15, quad = lane >> 4;
  const int m0 = blockIdx.y * 64, n0 = blockIdx.x * 128;
  const int wm = (wave & 1) * 32, wn = (wave >> 1) * 64;
  const int arow = tid >> 2, ac = (tid & 3) * 8;
  const short* asrc = A + (size_t)(m0 + arow) * 1024 + ac;
  const short* bsrc = WT + (size_t)(n0 + arow) * 1024 + ac;

  gl_lds16(asrc, &As[0][wave * 512]);
  gl_lds16(bsrc, &Bs[0][wave * 512]);
  gl_lds16(bsrc + 64 * 1024, &Bs[0][wave * 512 + 2048]);

  f32x4 acc[2][4] = {};
  for (int k = 0; k < 32; ++k) {
    const int cur = k & 1;
    __syncthreads();  // stage(k) landed; iter k-1 LDS reads drained
    if (k < 31) {
      const short* ap = asrc + (k + 1) * 32;
      const short* bp = bsrc + (k + 1) * 32;
      gl_lds16(ap, &As[1 - cur][wave * 512]);
      gl_lds16(bp, &Bs[1 - cur][wave * 512]);
      gl_lds16(bp + 64 * 1024, &Bs[1 - cur][wave * 512 + 2048]);
    }
    bf16x8 af[2], bfr[4];
#pragma unroll
    for (int i = 0; i < 2; ++i)
      af[i] = *(const bf16x8*)&As[cur][(wm + 16 * i + l15) * 32 + quad * 8];
#pragma unroll
    for (int j = 0; j < 4; ++j)
      bfr[j] = *(const bf16x8*)&Bs[cur][(wn + 16 * j + l15) * 32 + quad * 8];
#pragma unroll
    for (int i = 0; i < 2; ++i)
#pragma unroll
      for (int j = 0; j < 4; ++j) acc[i][j] = mfma16(af[i], bfr[j], acc[i][j]);
  }
#pragma unroll
  for (int j = 0; j < 4; ++j) {
    int col = n0 + wn + 16 * j + l15;
    float bv = bias[col];
    int reg = col >> 6;  // head-slot 0..39 (uniform across the 16 lanes)
    int d = col & 63;
#pragma unroll
    for (int i = 0; i < 2; ++i) {
#pragma unroll
      for (int r = 0; r < 4; ++r) {
        int row = m0 + wm + 16 * i + quad * 4 + r;
        int b = row >> 10, tok = row & 1023;
        if (reg < 16) {  // q: pre-scale by 0.125*log2e (softmax fold)
          unsigned short v = f2b(acc[i][j][r] * 0.18033688f);
          ((unsigned short*)qc)[((size_t)((b * 16 + reg) * 1024 + tok)) * 64 + d] = v;
        } else {
          unsigned short v = f2b(acc[i][j][r] + bv);
          if (reg < 32)
            ((unsigned short*)gc)[((size_t)((b * 16 + reg - 16) * 1024 + tok)) * 64 + d] = v;
          else if (reg < 36)
            ((unsigned short*)kc)[((size_t)((b * 4 + reg - 32) * 1024 + tok)) * 64 + d] = v;
          else
            ((unsigned short*)vt)[((size_t)((b * 4 + reg - 36) * 64 + d)) * 1024 + tok] = v;
        }
      }
    }
  }
}

// ---------------------------------------------------------------------------
// Output-projection GEMM (r7-proven): 64x64 tile, grid 16x64 = 1024 blocks,
// BK=32, double-buffered gl_lds, 4 waves = 2x2 of (32m x 32n).
// ---------------------------------------------------------------------------
__global__ __launch_bounds__(256, 4) void gemm_out(
    const short* __restrict__ A, const short* __restrict__ WT,
    float* __restrict__ Cout) {
  __shared__ short As[2][64 * 32];
  __shared__ short Bs[2][64 * 32];
  const int tid = threadIdx.x;
  const int wave = tid >> 6, lane = tid & 63, l15 = lane & 15, quad = lane >> 4;
  const int m0 = blockIdx.y * 64, n0 = blockIdx.x * 64;
  const int wm = (wave & 1) * 32, wn = (wave >> 1) * 32;
  const int arow = tid >> 2, ac = (tid & 3) * 8;
  const short* asrc = A + (size_t)(m0 + arow) * 1024 + ac;
  const short* bsrc = WT + (size_t)(n0 + arow) * 1024 + ac;

  gl_lds16(asrc, &As[0][wave * 512]);
  gl_lds16(bsrc, &Bs[0][wave * 512]);

  f32x4 acc[2][2] = {};
  for (int k = 0; k < 32; ++k) {
    const int cur = k & 1;
    __syncthreads();
    if (k < 31) {
      gl_lds16(asrc + (k + 1) * 32, &As[1 - cur][wave * 512]);
      gl_lds16(bsrc + (k + 1) * 32, &Bs[1 - cur][wave * 512]);
    }
    bf16x8 af[2], bfr[2];
#pragma unroll
    for (int i = 0; i < 2; ++i)
      af[i] = *(const bf16x8*)&As[cur][(wm + 16 * i + l15) * 32 + quad * 8];
#pragma unroll
    for (int j = 0; j < 2; ++j)
      bfr[j] = *(const bf16x8*)&Bs[cur][(wn + 16 * j + l15) * 32 + quad * 8];
#pragma unroll
    for (int i = 0; i < 2; ++i)
#pragma unroll
      for (int j = 0; j < 2; ++j) acc[i][j] = mfma16(af[i], bfr[j], acc[i][j]);
  }
#pragma unroll
  for (int j = 0; j < 2; ++j) {
    int col = n0 + wn + 16 * j + l15;
#pragma unroll
    for (int i = 0; i < 2; ++i) {
#pragma unroll
      for (int r = 0; r < 4; ++r) {
        int row = m0 + wm + 16 * i + quad * 4 + r;
        Cout[(size_t)row * 1024 + col] = acc[i][j][r];
      }
    }
  }
}

// ---------------------------------------------------------------------------
// MFMA flash attention + gate, round 15: in-register PV with 2x2 wave split.
// r12-r14 post-mortem: oacc=64 AGPRs ate half the 128-unified budget ->
// only 64 arch VGPRs -> qf/K/V spill-reloaded every kt (447MB scratch).
// Now wave w = (qh = w>>1, kh = w&1) owns 32 q rows x 32 keys-per-kt:
// oacc[2][4] = 32 AGPR, qf 16 + K 16 + V 16 + temps ~20 = ~70 arch.
// Total ~102 < 128 cap with headroom. Zero main-loop barriers; S output
// (col=l15=q, row=4quad+r=key) feeds the K=16 PV MFMA directly in-register.
// Cross-wave reduction: kh=0 waves write OA/OB (64d x 32q), kh=1 waves add.
// ---------------------------------------------------------------------------
__global__ __launch_bounds__(256, 4) void attn_mfma12(
    const short* __restrict__ qc, const short* __restrict__ gc,
    const short* __restrict__ kc, const short* __restrict__ vt,
    unsigned short* __restrict__ gated) {
  __shared__ float OA[64 * 33];  // qh=0 partial O^T [d][q&31]
  __shared__ float OB[64 * 33];  // qh=1
  __shared__ float Lpart[4 * 32];
  __shared__ float Lq[64];
  const int tid = threadIdx.x;
  const int w = tid >> 6, lane = tid & 63, l15 = lane & 15, quad = lane >> 4;
  const int qh = w >> 1, kh = w & 1;
  const int qt = blockIdx.x, bh = blockIdx.y, b = bh >> 4, h = bh & 15, kvh = h >> 2;

  // Q B-frags: col q = qt*64 + qh*32 + 16jq + l15, k = d = quad*8+i (+32)
  bf16x8 qf[2][2];
#pragma unroll
  for (int jq = 0; jq < 2; ++jq) {
    const short* qp = qc + ((size_t)((b * 16 + h) * 1024) + qt * 64 + qh * 32 +
                            16 * jq + l15) * 64 + quad * 8;
    qf[jq][0] = *(const bf16x8*)qp;
    qf[jq][1] = *(const bf16x8*)(qp + 32);
  }

  // K A-frag base: row key = kt*64 + kh*32 + {0,16} + l15 of kc[b,kvh,tok,64]
  const short* kbase =
      kc + ((size_t)((b * 4 + kvh) * 1024) + kh * 32 + l15) * 64 + quad * 8;
  // V A-frag base: row d = 16dt+l15 of vt[b,kvh,d,tok]; tok = kt*64+kh*32+...
  const short* vbase =
      vt + ((size_t)((b * 4 + kvh) * 64 + l15)) * 1024 + kh * 32 + quad * 4;

  f32x4 oacc[2][4] = {};  // [jq][dt]: d = 16dt+4quad+r, q = qh*32+16jq+l15
  float ls[2] = {0.f, 0.f};

  for (int kt = 0; kt < 16; ++kt) {
    const short* kp = kbase + (size_t)kt * 4096;
    const short* vp = vbase + kt * 64;
    bf16x8 kA0 = *(const bf16x8*)(kp);           // keysub 0, d 0-31
    bf16x8 kA1 = *(const bf16x8*)(kp + 32);      // keysub 0, d 32-63
    bf16x8 kB0 = *(const bf16x8*)(kp + 1024);    // keysub 1 (+16 rows)
    bf16x8 kB1 = *(const bf16x8*)(kp + 1056);
    bf16x4 vA0 = *(const bf16x4*)(vp);
    bf16x4 vA1 = *(const bf16x4*)(vp + 16384);
    bf16x4 vA2 = *(const bf16x4*)(vp + 32768);
    bf16x4 vA3 = *(const bf16x4*)(vp + 49152);
    bf16x4 vB0 = *(const bf16x4*)(vp + 16);
    bf16x4 vB1 = *(const bf16x4*)(vp + 16 + 16384);
    bf16x4 vB2 = *(const bf16x4*)(vp + 16 + 32768);
    bf16x4 vB3 = *(const bf16x4*)(vp + 16 + 49152);
#pragma unroll
    for (int jq = 0; jq < 2; ++jq) {
      {  // keysub 0
        f32x4 st = mfma16(kA0, qf[jq][0], (f32x4){0.f, 0.f, 0.f, 0.f});
        st = mfma16(kA1, qf[jq][1], st);
        float p0 = exp2f(st[0]);  // scale pre-folded into qc
        float p1 = exp2f(st[1]);
        float p2 = exp2f(st[2]);
        float p3 = exp2f(st[3]);
        ls[jq] += (p0 + p1) + (p2 + p3);
        bf16x4 pbf;
        pbf[0] = (short)f2b(p0);
        pbf[1] = (short)f2b(p1);
        pbf[2] = (short)f2b(p2);
        pbf[3] = (short)f2b(p3);
        oacc[jq][0] = mfma16k16(vA0, pbf, oacc[jq][0]);
        oacc[jq][1] = mfma16k16(vA1, pbf, oacc[jq][1]);
        oacc[jq][2] = mfma16k16(vA2, pbf, oacc[jq][2]);
        oacc[jq][3] = mfma16k16(vA3, pbf, oacc[jq][3]);
      }
      {  // keysub 1
        f32x4 st = mfma16(kB0, qf[jq][0], (f32x4){0.f, 0.f, 0.f, 0.f});
        st = mfma16(kB1, qf[jq][1], st);
        float p0 = exp2f(st[0]);
        float p1 = exp2f(st[1]);
        float p2 = exp2f(st[2]);
        float p3 = exp2f(st[3]);
        ls[jq] += (p0 + p1) + (p2 + p3);
        bf16x4 pbf;
        pbf[0] = (short)f2b(p0);
        pbf[1] = (short)f2b(p1);
        pbf[2] = (short)f2b(p2);
        pbf[3] = (short)f2b(p3);
        oacc[jq][0] = mfma16k16(vB0, pbf, oacc[jq][0]);
        oacc[jq][1] = mfma16k16(vB1, pbf, oacc[jq][1]);
        oacc[jq][2] = mfma16k16(vB2, pbf, oacc[jq][2]);
        oacc[jq][3] = mfma16k16(vB3, pbf, oacc[jq][3]);
      }
    }
  }

  // l reduction: quad-reduce in-wave (sum over this wave's 512 keys per q)
#pragma unroll
  for (int jq = 0; jq < 2; ++jq) {
    ls[jq] += __shfl_xor(ls[jq], 16);
    ls[jq] += __shfl_xor(ls[jq], 32);
  }
  if (quad == 0) {
#pragma unroll
    for (int jq = 0; jq < 2; ++jq) Lpart[w * 32 + 16 * jq + l15] = ls[jq];
  }

  // cross-wave O reduction: kh=0 waves write their qh buffer; kh=1 waves add.
  float* Ob = qh ? OB : OA;
  if (kh == 0) {
#pragma unroll
    for (int jq = 0; jq < 2; ++jq)
#pragma unroll
      for (int dt = 0; dt < 4; ++dt)
#pragma unroll
        for (int r = 0; r < 4; ++r)
          Ob[(16 * dt + 4 * quad + r) * 33 + 16 * jq + l15] = oacc[jq][dt][r];
  }
  __syncthreads();
  if (kh == 1) {
#pragma unroll
    for (int jq = 0; jq < 2; ++jq)
#pragma unroll
      for (int dt = 0; dt < 4; ++dt)
#pragma unroll
        for (int r = 0; r < 4; ++r)
          Ob[(16 * dt + 4 * quad + r) * 33 + 16 * jq + l15] += oacc[jq][dt][r];
  }
  if (tid < 64) {
    int ql = tid & 31, qh2 = tid >> 5;
    Lq[tid] = Lpart[qh2 * 64 + ql] + Lpart[qh2 * 64 + 32 + ql];
  }
  __syncthreads();

  // epilogue: O rows q = 16jq+4quad+r (jq 0..3), cols d = 16w+l15
  const int d = 16 * w + l15;
#pragma unroll
  for (int jq = 0; jq < 4; ++jq) {
    const float* Osrc = (jq < 2) ? OA : OB;
#pragma unroll
    for (int r = 0; r < 4; ++r) {
      int qloc = 16 * jq + 4 * quad + r;
      float ov = Osrc[d * 33 + (qloc & 31)];
      float lv = Lq[qloc];
      float gv = b2f(((const unsigned short*)gc)[
          ((size_t)((b * 16 + h) * 1024) + qt * 64 + qloc) * 64 + d]);
      size_t row = (size_t)(b * NN + qt * 64 + qloc);
      gated[row * 1024 + h * 64 + d] = f2b(ov / lv * gv);
    }
  }
}

// ---------------------------------------------------------------------------
extern "C" void kernel_launch(void* const* d_in, const int* in_sizes, int n_in,
                              void* d_out, int out_size, void* d_ws,
                              size_t ws_size, hipStream_t stream) {
  const float* x = (const float*)d_in[0];
  const float* Wq = (const float*)d_in[1];
  const float* Wkv = (const float*)d_in[2];
  const float* Wg = (const float*)d_in[3];
  const float* bg = (const float*)d_in[4];
  const float* Wo = (const float*)d_in[5];
  float* out = (float*)d_out;

  // ws layout (short elems): ~36.6 MB total
  short* ws = (short*)d_ws;
  short* xb = ws;                     // 4.19M (x bf16; later aliased as gated)
  short* WcT = xb + 4194304;          // 2.62M (W^T combined: q|g|kv rows)
  short* WoT = WcT + 2621440;         // 1.05M
  short* qc = WoT + 1048576;          // 4.19M  q[b,h,tok,d]
  short* gc = qc + 4194304;           // 4.19M  gate[b,h,tok,d]
  short* kc = gc + 4194304;           // 1.05M  k[b,kvh,tok,d]
  short* vtw = kc + 1048576;          // 1.05M  v^T[b,kvh,d,tok]
  float* bias_f32 = (float*)(vtw + 1048576);  // 2560 f32

  dim3 blk(256);
  // weight transposes + bias + x-convert, one dispatch
  transpose_all<<<dim3(16, 16, 6), blk, 0, stream>>>(Wq, Wkv, Wg, Wo, bg, x,
                                                     WcT, WoT, bias_f32, xb);
  // fused q|gate|kv projection (outputs diverted to compact layouts)
  gemm_proj<<<dim3(20, 64), blk, 0, stream>>>(xb, WcT, bias_f32, qc, gc, kc, vtw);
  // attention + gate -> gated (aliases xb; xb no longer needed)
  attn_mfma12<<<dim3(16, 64), blk, 0, stream>>>(qc, gc, kc, vtw, (unsigned short*)xb);
  // output projection
  gemm_out<<<dim3(16, 64), blk, 0, stream>>>(xb, WoT, out);
}

// Round 6
// 239.026 us; speedup vs baseline: 1.2388x; 1.0042x over previous
//
#include <hip/hip_runtime.h>
#include <hip/hip_bf16.h>
#include <stdint.h>

#define BB 4
#define NN 1024
#define DD 1024
#define HH 16
#define HDIM 64
#define KVHH 4
#define MM (BB * NN)  // 4096 token rows

typedef __hip_bfloat16 bf16;
typedef __attribute__((ext_vector_type(8))) short bf16x8;  // 8 bf16 = 4 VGPR
typedef __attribute__((ext_vector_type(4))) short bf16x4;  // 4 bf16 = 2 VGPR
typedef __attribute__((ext_vector_type(4))) float f32x4;

__device__ __forceinline__ float b2f(unsigned short u) {
  return __uint_as_float(((unsigned)u) << 16);
}
__device__ __forceinline__ unsigned short f2b(float x) {
  bf16 h = __float2bfloat16(x);
  unsigned short u;
  __builtin_memcpy(&u, &h, 2);
  return u;
}
__device__ __forceinline__ f32x4 mfma16(bf16x8 a, bf16x8 b, f32x4 c) {
  return __builtin_amdgcn_mfma_f32_16x16x32_bf16(a, b, c, 0, 0, 0);
}
// K=16 MFMA: B-fragment layout (col=l15, k=quad*4+i) matches the K=32 MFMA's
// C layout (col=l15, row=quad*4+r) -> S output feeds PV directly, in-register.
// (Correctness HW-verified r12-r15: absmax identical across all rounds.)
__device__ __forceinline__ f32x4 mfma16k16(bf16x4 a, bf16x4 b, f32x4 c) {
#if __has_builtin(__builtin_amdgcn_mfma_f32_16x16x16bf16_1k)
  return __builtin_amdgcn_mfma_f32_16x16x16bf16_1k(a, b, c, 0, 0, 0);
#else
  asm("s_nop 1\n\tv_mfma_f32_16x16x16_bf16 %0, %1, %2, %0"
      : "+v"(c)
      : "v"(a), "v"(b));
  return c;
#endif
}
__device__ __forceinline__ void gl_lds16(const short* g, short* l) {
  __builtin_amdgcn_global_load_lds(
      (const __attribute__((address_space(1))) unsigned*)g,
      (__attribute__((address_space(3))) unsigned*)l, 16, 0, 0);
}

// ---------------------------------------------------------------------------
// z=0..3: weight transposes W (K x N fp32) -> WT (N x K bf16), 64x64 tiles.
// z=4: combined bias build. z=5: x fp32 -> bf16 convert.
// ---------------------------------------------------------------------------
__global__ __launch_bounds__(256) void transpose_all(
    const float* __restrict__ Wq, const float* __restrict__ Wkv,
    const float* __restrict__ Wg, const float* __restrict__ Wo,
    const float* __restrict__ bg, const float* __restrict__ x,
    short* __restrict__ WcT, short* __restrict__ WoT,
    float* __restrict__ bias, short* __restrict__ xb) {
  const int z = blockIdx.z;
  if (z == 4) {  // combined bias: [0,1024)=0, [1024,2048)=bg, [2048,2560)=0
    if (blockIdx.y == 0 && blockIdx.x < 10) {
      int i = blockIdx.x * 256 + threadIdx.x;
      if (i < 2560) bias[i] = (i >= 1024 && i < 2048) ? bg[i - 1024] : 0.f;
    }
    return;
  }
  if (z == 5) {  // x convert: 256 blocks x 256 threads x 16 float4
    int base = (blockIdx.y * 16 + blockIdx.x) * 256 + threadIdx.x;
#pragma unroll
    for (int it = 0; it < 16; ++it) {
      int i = base + it * 65536;
      float4 v = *(const float4*)&x[(size_t)i * 4];
      ushort4 o;
      o.x = f2b(v.x); o.y = f2b(v.y); o.z = f2b(v.z); o.w = f2b(v.w);
      *(ushort4*)&xb[(size_t)i * 4] = o;
    }
    return;
  }
  const float* W;
  short* WT;
  int N = 1024;
  const int K = 1024;
  if (z == 0) { W = Wq; WT = WcT; }
  else if (z == 1) { W = Wg; WT = WcT + 1048576; }
  else if (z == 2) {
    W = Wkv; WT = WcT + 2097152; N = 512;
    if (blockIdx.x >= 8) return;  // uniform early-out, before any sync
  } else { W = Wo; WT = WoT; }

  __shared__ short T[64 * 68];
  const int tid = threadIdx.x;
  const int n0 = blockIdx.x * 64, k0 = blockIdx.y * 64;
  {
    int i0 = tid >> 4, j4 = (tid & 15) * 4;
#pragma unroll
    for (int ii = 0; ii < 4; ++ii) {
      int i = i0 + 16 * ii;
      float4 w = *(const float4*)&W[(size_t)(k0 + i) * N + n0 + j4];
      ushort4 o;
      o.x = f2b(w.x); o.y = f2b(w.y); o.z = f2b(w.z); o.w = f2b(w.w);
      *(ushort4*)&T[i * 68 + j4] = o;
    }
  }
  __syncthreads();
  {
    int n = tid >> 2, k16 = (tid & 3) * 16;
    short tmp[16];
#pragma unroll
    for (int kk = 0; kk < 16; ++kk) tmp[kk] = T[(k16 + kk) * 68 + n];
    short* dst = WT + (size_t)(n0 + n) * K + k0 + k16;
#pragma unroll
    for (int s = 0; s < 16; s += 4) *(ushort4*)&dst[s] = *(const ushort4*)&tmp[s];
  }
}

// ---------------------------------------------------------------------------
// Fused projection GEMM: 64x128 tile (grid 20x64 = 1280 blocks = 5/CU), BK=32,
// double-buffered gl_lds. Epilogue diverts to compact head-major buffers.
// q-head outputs are pre-scaled by log2e/8 so attention's softmax is bare exp2.
// ---------------------------------------------------------------------------
__global__ __launch_bounds__(256, 5) void gemm_proj(
    const short* __restrict__ A, const short* __restrict__ WT,
    const float* __restrict__ bias, short* __restrict__ qc,
    short* __restrict__ gc, short* __restrict__ kc, short* __restrict__ vt) {
  __shared__ short As[2][64 * 32];
  __shared__ short Bs[2][128 * 32];
  const int tid = threadIdx.x;
  const int wave = tid >> 6, lane = tid & 63, l15 = lane & 15, quad = lane >> 4;
  const int m0 = blockIdx.y * 64, n0 = blockIdx.x * 128;
  const int wm = (wave & 1) * 32, wn = (wave >> 1) * 64;
  const int arow = tid >> 2, ac = (tid & 3) * 8;
  const short* asrc = A + (size_t)(m0 + arow) * 1024 + ac;
  const short* bsrc = WT + (size_t)(n0 + arow) * 1024 + ac;

  gl_lds16(asrc, &As[0][wave * 512]);
  gl_lds16(bsrc, &Bs[0][wave * 512]);
  gl_lds16(bsrc + 64 * 1024, &Bs[0][wave * 512 + 2048]);

  f32x4 acc[2][4] = {};
  for (int k = 0; k < 32; ++k) {
    const int cur = k & 1;
    __syncthreads();  // stage(k) landed; iter k-1 LDS reads drained
    if (k < 31) {
      const short* ap = asrc + (k + 1) * 32;
      const short* bp = bsrc + (k + 1) * 32;
      gl_lds16(ap, &As[1 - cur][wave * 512]);
      gl_lds16(bp, &Bs[1 - cur][wave * 512]);
      gl_lds16(bp + 64 * 1024, &Bs[1 - cur][wave * 512 + 2048]);
    }
    bf16x8 af[2], bfr[4];
#pragma unroll
    for (int i = 0; i < 2; ++i)
      af[i] = *(const bf16x8*)&As[cur][(wm + 16 * i + l15) * 32 + quad * 8];
#pragma unroll
    for (int j = 0; j < 4; ++j)
      bfr[j] = *(const bf16x8*)&Bs[cur][(wn + 16 * j + l15) * 32 + quad * 8];
#pragma unroll
    for (int i = 0; i < 2; ++i)
#pragma unroll
      for (int j = 0; j < 4; ++j) acc[i][j] = mfma16(af[i], bfr[j], acc[i][j]);
  }
#pragma unroll
  for (int j = 0; j < 4; ++j) {
    int col = n0 + wn + 16 * j + l15;
    float bv = bias[col];
    int reg = col >> 6;  // head-slot 0..39 (uniform across the 16 lanes)
    int d = col & 63;
#pragma unroll
    for (int i = 0; i < 2; ++i) {
#pragma unroll
      for (int r = 0; r < 4; ++r) {
        int row = m0 + wm + 16 * i + quad * 4 + r;
        int b = row >> 10, tok = row & 1023;
        if (reg < 16) {  // q: pre-scale by 0.125*log2e (softmax fold)
          unsigned short v = f2b(acc[i][j][r] * 0.18033688f);
          ((unsigned short*)qc)[((size_t)((b * 16 + reg) * 1024 + tok)) * 64 + d] = v;
        } else {
          unsigned short v = f2b(acc[i][j][r] + bv);
          if (reg < 32)
            ((unsigned short*)gc)[((size_t)((b * 16 + reg - 16) * 1024 + tok)) * 64 + d] = v;
          else if (reg < 36)
            ((unsigned short*)kc)[((size_t)((b * 4 + reg - 32) * 1024 + tok)) * 64 + d] = v;
          else
            ((unsigned short*)vt)[((size_t)((b * 4 + reg - 36) * 64 + d)) * 1024 + tok] = v;
        }
      }
    }
  }
}

// ---------------------------------------------------------------------------
// Output-projection GEMM (r7-proven): 64x64 tile, grid 16x64 = 1024 blocks,
// BK=32, double-buffered gl_lds, 4 waves = 2x2 of (32m x 32n).
// ---------------------------------------------------------------------------
__global__ __launch_bounds__(256, 4) void gemm_out(
    const short* __restrict__ A, const short* __restrict__ WT,
    float* __restrict__ Cout) {
  __shared__ short As[2][64 * 32];
  __shared__ short Bs[2][64 * 32];
  const int tid = threadIdx.x;
  const int wave = tid >> 6, lane = tid & 63, l15 = lane & 15, quad = lane >> 4;
  const int m0 = blockIdx.y * 64, n0 = blockIdx.x * 64;
  const int wm = (wave & 1) * 32, wn = (wave >> 1) * 32;
  const int arow = tid >> 2, ac = (tid & 3) * 8;
  const short* asrc = A + (size_t)(m0 + arow) * 1024 + ac;
  const short* bsrc = WT + (size_t)(n0 + arow) * 1024 + ac;

  gl_lds16(asrc, &As[0][wave * 512]);
  gl_lds16(bsrc, &Bs[0][wave * 512]);

  f32x4 acc[2][2] = {};
  for (int k = 0; k < 32; ++k) {
    const int cur = k & 1;
    __syncthreads();
    if (k < 31) {
      gl_lds16(asrc + (k + 1) * 32, &As[1 - cur][wave * 512]);
      gl_lds16(bsrc + (k + 1) * 32, &Bs[1 - cur][wave * 512]);
    }
    bf16x8 af[2], bfr[2];
#pragma unroll
    for (int i = 0; i < 2; ++i)
      af[i] = *(const bf16x8*)&As[cur][(wm + 16 * i + l15) * 32 + quad * 8];
#pragma unroll
    for (int j = 0; j < 2; ++j)
      bfr[j] = *(const bf16x8*)&Bs[cur][(wn + 16 * j + l15) * 32 + quad * 8];
#pragma unroll
    for (int i = 0; i < 2; ++i)
#pragma unroll
      for (int j = 0; j < 2; ++j) acc[i][j] = mfma16(af[i], bfr[j], acc[i][j]);
  }
#pragma unroll
  for (int j = 0; j < 2; ++j) {
    int col = n0 + wn + 16 * j + l15;
#pragma unroll
    for (int i = 0; i < 2; ++i) {
#pragma unroll
      for (int r = 0; r < 4; ++r) {
        int row = m0 + wm + 16 * i + quad * 4 + r;
        Cout[(size_t)row * 1024 + col] = acc[i][j][r];
      }
    }
  }
}

// ---------------------------------------------------------------------------
// MFMA flash attention + gate, round 16: r15's 2x2 wave split + SAME-REGISTER
// prefetch-distance-1. r15 post-mortem: no spill but latency-bound (MfmaUtil
// 10%, VALU 22%, HBM 4% -- single-buffered loads stall every kt). Now each
// K sub-fragment's next-kt load issues immediately AFTER its last S-MFMA use
// (same register names, no extra buffers), and V's next-kt loads issue after
// PV consumes them -- every load gets ~half-to-full iteration (~300-500 cyc)
// of MFMA+exp2 cover. Register budget: qf 16 + K 16 + V 16 + st 8 + temps
// ~20 = ~90 arch + 32 acc oacc < 128 unified cap at (256,4).
// ---------------------------------------------------------------------------
__global__ __launch_bounds__(256, 4) void attn_mfma13(
    const short* __restrict__ qc, const short* __restrict__ gc,
    const short* __restrict__ kc, const short* __restrict__ vt,
    unsigned short* __restrict__ gated) {
  __shared__ float OA[64 * 33];  // qh=0 partial O^T [d][q&31]
  __shared__ float OB[64 * 33];  // qh=1
  __shared__ float Lpart[4 * 32];
  __shared__ float Lq[64];
  const int tid = threadIdx.x;
  const int w = tid >> 6, lane = tid & 63, l15 = lane & 15, quad = lane >> 4;
  const int qh = w >> 1, kh = w & 1;
  const int qt = blockIdx.x, bh = blockIdx.y, b = bh >> 4, h = bh & 15, kvh = h >> 2;

  // Q B-frags: col q = qt*64 + qh*32 + 16jq + l15, k = d = quad*8+i (+32)
  bf16x8 qf[2][2];
#pragma unroll
  for (int jq = 0; jq < 2; ++jq) {
    const short* qp = qc + ((size_t)((b * 16 + h) * 1024) + qt * 64 + qh * 32 +
                            16 * jq + l15) * 64 + quad * 8;
    qf[jq][0] = *(const bf16x8*)qp;
    qf[jq][1] = *(const bf16x8*)(qp + 32);
  }

  // K A-frag base: row key = kt*64 + kh*32 + {0,16} + l15 of kc[b,kvh,tok,64]
  const short* kp =
      kc + ((size_t)((b * 4 + kvh) * 1024) + kh * 32 + l15) * 64 + quad * 8;
  // V A-frag base: row d = 16dt+l15 of vt[b,kvh,d,tok]; tok = kt*64+kh*32+...
  const short* vp =
      vt + ((size_t)((b * 4 + kvh) * 64 + l15)) * 1024 + kh * 32 + quad * 4;

  f32x4 oacc[2][4] = {};  // [jq][dt]: d = 16dt+4quad+r, q = qh*32+16jq+l15
  float ls[2] = {0.f, 0.f};

  // K(0), V(0) preload (single named set; prefetch re-writes same names)
  bf16x8 kA0 = *(const bf16x8*)(kp);           // keysub 0, d 0-31
  bf16x8 kA1 = *(const bf16x8*)(kp + 32);      // keysub 0, d 32-63
  bf16x8 kA2 = *(const bf16x8*)(kp + 1024);    // keysub 1 (+16 rows)
  bf16x8 kA3 = *(const bf16x8*)(kp + 1056);
  bf16x4 v0 = *(const bf16x4*)(vp);
  bf16x4 v1 = *(const bf16x4*)(vp + 16384);
  bf16x4 v2 = *(const bf16x4*)(vp + 32768);
  bf16x4 v3 = *(const bf16x4*)(vp + 49152);
  bf16x4 v4 = *(const bf16x4*)(vp + 16);
  bf16x4 v5 = *(const bf16x4*)(vp + 16 + 16384);
  bf16x4 v6 = *(const bf16x4*)(vp + 16 + 32768);
  bf16x4 v7 = *(const bf16x4*)(vp + 16 + 49152);

#define EXPPV(ST, JQ, VA, VB, VC, VD)                                          \
  {                                                                            \
    float p0 = exp2f((ST)[0]), p1 = exp2f((ST)[1]);                            \
    float p2 = exp2f((ST)[2]), p3 = exp2f((ST)[3]);                            \
    ls[JQ] += (p0 + p1) + (p2 + p3);                                           \
    bf16x4 pbf;                                                                \
    pbf[0] = (short)f2b(p0);                                                   \
    pbf[1] = (short)f2b(p1);                                                   \
    pbf[2] = (short)f2b(p2);                                                   \
    pbf[3] = (short)f2b(p3);                                                   \
    oacc[JQ][0] = mfma16k16((VA), pbf, oacc[JQ][0]);                           \
    oacc[JQ][1] = mfma16k16((VB), pbf, oacc[JQ][1]);                           \
    oacc[JQ][2] = mfma16k16((VC), pbf, oacc[JQ][2]);                           \
    oacc[JQ][3] = mfma16k16((VD), pbf, oacc[JQ][3]);                           \
  }

  for (int kt = 0; kt < 16; ++kt) {
    const short* kn = kp + 4096;  // K(kt+1)
    const short* vn = vp + 64;    // V(kt+1)
    // ---- S phase keysub0 (kA0/kA1 last use), both jq chains
    f32x4 s00 = mfma16(kA0, qf[0][0], (f32x4){0.f, 0.f, 0.f, 0.f});
    s00 = mfma16(kA1, qf[0][1], s00);
    f32x4 s10 = mfma16(kA0, qf[1][0], (f32x4){0.f, 0.f, 0.f, 0.f});
    s10 = mfma16(kA1, qf[1][1], s10);
    if (kt < 15) {  // prefetch next keysub0 K into the same regs
      kA0 = *(const bf16x8*)(kn);
      kA1 = *(const bf16x8*)(kn + 32);
    }
    EXPPV(s00, 0, v0, v1, v2, v3);
    EXPPV(s10, 1, v0, v1, v2, v3);
    // ---- S phase keysub1 (kA2/kA3 last use)
    f32x4 s01 = mfma16(kA2, qf[0][0], (f32x4){0.f, 0.f, 0.f, 0.f});
    s01 = mfma16(kA3, qf[0][1], s01);
    f32x4 s11 = mfma16(kA2, qf[1][0], (f32x4){0.f, 0.f, 0.f, 0.f});
    s11 = mfma16(kA3, qf[1][1], s11);
    if (kt < 15) {
      kA2 = *(const bf16x8*)(kn + 1024);
      kA3 = *(const bf16x8*)(kn + 1056);
    }
    EXPPV(s01, 0, v4, v5, v6, v7);
    EXPPV(s11, 1, v4, v5, v6, v7);
    if (kt < 15) {  // V(kt+1): v regs dead after the PV above
      v0 = *(const bf16x4*)(vn);
      v1 = *(const bf16x4*)(vn + 16384);
      v2 = *(const bf16x4*)(vn + 32768);
      v3 = *(const bf16x4*)(vn + 49152);
      v4 = *(const bf16x4*)(vn + 16);
      v5 = *(const bf16x4*)(vn + 16 + 16384);
      v6 = *(const bf16x4*)(vn + 16 + 32768);
      v7 = *(const bf16x4*)(vn + 16 + 49152);
    }
    kp = kn;
    vp = vn;
  }
#undef EXPPV

  // l reduction: quad-reduce in-wave (sum over this wave's 512 keys per q)
#pragma unroll
  for (int jq = 0; jq < 2; ++jq) {
    ls[jq] += __shfl_xor(ls[jq], 16);
    ls[jq] += __shfl_xor(ls[jq], 32);
  }
  if (quad == 0) {
#pragma unroll
    for (int jq = 0; jq < 2; ++jq) Lpart[w * 32 + 16 * jq + l15] = ls[jq];
  }

  // cross-wave O reduction: kh=0 waves write their qh buffer; kh=1 waves add.
  float* Ob = qh ? OB : OA;
  if (kh == 0) {
#pragma unroll
    for (int jq = 0; jq < 2; ++jq)
#pragma unroll
      for (int dt = 0; dt < 4; ++dt)
#pragma unroll
        for (int r = 0; r < 4; ++r)
          Ob[(16 * dt + 4 * quad + r) * 33 + 16 * jq + l15] = oacc[jq][dt][r];
  }
  __syncthreads();
  if (kh == 1) {
#pragma unroll
    for (int jq = 0; jq < 2; ++jq)
#pragma unroll
      for (int dt = 0; dt < 4; ++dt)
#pragma unroll
        for (int r = 0; r < 4; ++r)
          Ob[(16 * dt + 4 * quad + r) * 33 + 16 * jq + l15] += oacc[jq][dt][r];
  }
  if (tid < 64) {
    int ql = tid & 31, qh2 = tid >> 5;
    Lq[tid] = Lpart[qh2 * 64 + ql] + Lpart[qh2 * 64 + 32 + ql];
  }
  __syncthreads();

  // epilogue: O rows q = 16jq+4quad+r (jq 0..3), cols d = 16w+l15
  const int d = 16 * w + l15;
#pragma unroll
  for (int jq = 0; jq < 4; ++jq) {
    const float* Osrc = (jq < 2) ? OA : OB;
#pragma unroll
    for (int r = 0; r < 4; ++r) {
      int qloc = 16 * jq + 4 * quad + r;
      float ov = Osrc[d * 33 + (qloc & 31)];
      float lv = Lq[qloc];
      float gv = b2f(((const unsigned short*)gc)[
          ((size_t)((b * 16 + h) * 1024) + qt * 64 + qloc) * 64 + d]);
      size_t row = (size_t)(b * NN + qt * 64 + qloc);
      gated[row * 1024 + h * 64 + d] = f2b(ov / lv * gv);
    }
  }
}

// ---------------------------------------------------------------------------
extern "C" void kernel_launch(void* const* d_in, const int* in_sizes, int n_in,
                              void* d_out, int out_size, void* d_ws,
                              size_t ws_size, hipStream_t stream) {
  const float* x = (const float*)d_in[0];
  const float* Wq = (const float*)d_in[1];
  const float* Wkv = (const float*)d_in[2];
  const float* Wg = (const float*)d_in[3];
  const float* bg = (const float*)d_in[4];
  const float* Wo = (const float*)d_in[5];
  float* out = (float*)d_out;

  // ws layout (short elems): ~36.6 MB total
  short* ws = (short*)d_ws;
  short* xb = ws;                     // 4.19M (x bf16; later aliased as gated)
  short* WcT = xb + 4194304;          // 2.62M (W^T combined: q|g|kv rows)
  short* WoT = WcT + 2621440;         // 1.05M
  short* qc = WoT + 1048576;          // 4.19M  q[b,h,tok,d]
  short* gc = qc + 4194304;           // 4.19M  gate[b,h,tok,d]
  short* kc = gc + 4194304;           // 1.05M  k[b,kvh,tok,d]
  short* vtw = kc + 1048576;          // 1.05M  v^T[b,kvh,d,tok]
  float* bias_f32 = (float*)(vtw + 1048576);  // 2560 f32

  dim3 blk(256);
  // weight transposes + bias + x-convert, one dispatch
  transpose_all<<<dim3(16, 16, 6), blk, 0, stream>>>(Wq, Wkv, Wg, Wo, bg, x,
                                                     WcT, WoT, bias_f32, xb);
  // fused q|gate|kv projection (outputs diverted to compact layouts)
  gemm_proj<<<dim3(20, 64), blk, 0, stream>>>(xb, WcT, bias_f32, qc, gc, kc, vtw);
  // attention + gate -> gated (aliases xb; xb no longer needed)
  attn_mfma13<<<dim3(16, 64), blk, 0, stream>>>(qc, gc, kc, vtw, (unsigned short*)xb);
  // output projection
  gemm_out<<<dim3(16, 64), blk, 0, stream>>>(xb, WoT, out);
}

// Round 7
// 177.529 us; speedup vs baseline: 1.6679x; 1.3464x over previous
//
#include <hip/hip_runtime.h>
#include <hip/hip_bf16.h>
#include <stdint.h>

#define BB 4
#define NN 1024
#define DD 1024
#define HH 16
#define HDIM 64
#define KVHH 4
#define MM (BB * NN)  // 4096 token rows

typedef __hip_bfloat16 bf16;
typedef __attribute__((ext_vector_type(8))) short bf16x8;  // 8 bf16 = 4 VGPR
typedef __attribute__((ext_vector_type(4))) short bf16x4;  // 4 bf16 = 2 VGPR
typedef __attribute__((ext_vector_type(4))) float f32x4;

__device__ __forceinline__ float b2f(unsigned short u) {
  return __uint_as_float(((unsigned)u) << 16);
}
__device__ __forceinline__ unsigned short f2b(float x) {
  bf16 h = __float2bfloat16(x);
  unsigned short u;
  __builtin_memcpy(&u, &h, 2);
  return u;
}
__device__ __forceinline__ f32x4 mfma16(bf16x8 a, bf16x8 b, f32x4 c) {
  return __builtin_amdgcn_mfma_f32_16x16x32_bf16(a, b, c, 0, 0, 0);
}
// K=16 MFMA: B-fragment layout (col=l15, k=quad*4+i) matches the K=32 MFMA's
// C layout (col=l15, row=quad*4+r) -> S output feeds PV directly, in-register.
// (Correctness HW-verified r12-r16: absmax identical across all rounds.)
__device__ __forceinline__ f32x4 mfma16k16(bf16x4 a, bf16x4 b, f32x4 c) {
#if __has_builtin(__builtin_amdgcn_mfma_f32_16x16x16bf16_1k)
  return __builtin_amdgcn_mfma_f32_16x16x16bf16_1k(a, b, c, 0, 0, 0);
#else
  asm("s_nop 1\n\tv_mfma_f32_16x16x16_bf16 %0, %1, %2, %0"
      : "+v"(c)
      : "v"(a), "v"(b));
  return c;
#endif
}
__device__ __forceinline__ bf16x4 vlo(bf16x8 v) {
  return __builtin_shufflevector(v, v, 0, 1, 2, 3);
}
__device__ __forceinline__ bf16x4 vhi(bf16x8 v) {
  return __builtin_shufflevector(v, v, 4, 5, 6, 7);
}
__device__ __forceinline__ void gl_lds16(const short* g, short* l) {
  __builtin_amdgcn_global_load_lds(
      (const __attribute__((address_space(1))) unsigned*)g,
      (__attribute__((address_space(3))) unsigned*)l, 16, 0, 0);
}

// ---------------------------------------------------------------------------
// z=0..3: weight transposes W (K x N fp32) -> WT (N x K bf16), 64x64 tiles.
// z=4: combined bias build. z=5: x fp32 -> bf16 convert.
// ---------------------------------------------------------------------------
__global__ __launch_bounds__(256) void transpose_all(
    const float* __restrict__ Wq, const float* __restrict__ Wkv,
    const float* __restrict__ Wg, const float* __restrict__ Wo,
    const float* __restrict__ bg, const float* __restrict__ x,
    short* __restrict__ WcT, short* __restrict__ WoT,
    float* __restrict__ bias, short* __restrict__ xb) {
  const int z = blockIdx.z;
  if (z == 4) {  // combined bias: [0,1024)=0, [1024,2048)=bg, [2048,2560)=0
    if (blockIdx.y == 0 && blockIdx.x < 10) {
      int i = blockIdx.x * 256 + threadIdx.x;
      if (i < 2560) bias[i] = (i >= 1024 && i < 2048) ? bg[i - 1024] : 0.f;
    }
    return;
  }
  if (z == 5) {  // x convert: 256 blocks x 256 threads x 16 float4
    int base = (blockIdx.y * 16 + blockIdx.x) * 256 + threadIdx.x;
#pragma unroll
    for (int it = 0; it < 16; ++it) {
      int i = base + it * 65536;
      float4 v = *(const float4*)&x[(size_t)i * 4];
      ushort4 o;
      o.x = f2b(v.x); o.y = f2b(v.y); o.z = f2b(v.z); o.w = f2b(v.w);
      *(ushort4*)&xb[(size_t)i * 4] = o;
    }
    return;
  }
  const float* W;
  short* WT;
  int N = 1024;
  const int K = 1024;
  if (z == 0) { W = Wq; WT = WcT; }
  else if (z == 1) { W = Wg; WT = WcT + 1048576; }
  else if (z == 2) {
    W = Wkv; WT = WcT + 2097152; N = 512;
    if (blockIdx.x >= 8) return;  // uniform early-out, before any sync
  } else { W = Wo; WT = WoT; }

  __shared__ short T[64 * 68];
  const int tid = threadIdx.x;
  const int n0 = blockIdx.x * 64, k0 = blockIdx.y * 64;
  {
    int i0 = tid >> 4, j4 = (tid & 15) * 4;
#pragma unroll
    for (int ii = 0; ii < 4; ++ii) {
      int i = i0 + 16 * ii;
      float4 w = *(const float4*)&W[(size_t)(k0 + i) * N + n0 + j4];
      ushort4 o;
      o.x = f2b(w.x); o.y = f2b(w.y); o.z = f2b(w.z); o.w = f2b(w.w);
      *(ushort4*)&T[i * 68 + j4] = o;
    }
  }
  __syncthreads();
  {
    int n = tid >> 2, k16 = (tid & 3) * 16;
    short tmp[16];
#pragma unroll
    for (int kk = 0; kk < 16; ++kk) tmp[kk] = T[(k16 + kk) * 68 + n];
    short* dst = WT + (size_t)(n0 + n) * K + k0 + k16;
#pragma unroll
    for (int s = 0; s < 16; s += 4) *(ushort4*)&dst[s] = *(const ushort4*)&tmp[s];
  }
}

// ---------------------------------------------------------------------------
// Fused projection GEMM: 64x128 tile, BK=32, double-buffered gl_lds.
// Epilogue: q pre-scaled by log2e/8; K/V stored in FRAGMENT-PACKED layouts so
// the attention kernel's loads are fully lane-coalesced (r16 post-mortem: the
// old tok-major K/V made attn issue 12 scattered loads/wave/kt -> TA-bound).
// K pack: [(b*4+kvh)][kt*2+kh][chunk=ksub*2+dh][lane=dq*16+kl][di]  (8 sh/lane)
// V pack: [(b*4+kvh)][kt*2+kh][pair=ksub*2+(dt>>1)][lane=quad*16+dl][(dt&1)*4+r]
// ---------------------------------------------------------------------------
__global__ __launch_bounds__(256, 5) void gemm_proj(
    const short* __restrict__ A, const short* __restrict__ WT,
    const float* __restrict__ bias, short* __restrict__ qc,
    short* __restrict__ gc, short* __restrict__ kc, short* __restrict__ vt) {
  __shared__ short As[2][64 * 32];
  __shared__ short Bs[2][128 * 32];
  const int tid = threadIdx.x;
  const int wave = tid >> 6, lane = tid & 63, l15 = lane & 15, quad = lane >> 4;
  const int m0 = blockIdx.y * 64, n0 = blockIdx.x * 128;
  const int wm = (wave & 1) * 32, wn = (wave >> 1) * 64;
  const int arow = tid >> 2, ac = (tid & 3) * 8;
  const short* asrc = A + (size_t)(m0 + arow) * 1024 + ac;
  const short* bsrc = WT + (size_t)(n0 + arow) * 1024 + ac;

  gl_lds16(asrc, &As[0][wave * 512]);
  gl_lds16(bsrc, &Bs[0][wave * 512]);
  gl_lds16(bsrc + 64 * 1024, &Bs[0][wave * 512 + 2048]);

  f32x4 acc[2][4] = {};
  for (int k = 0; k < 32; ++k) {
    const int cur = k & 1;
    __syncthreads();  // stage(k) landed; iter k-1 LDS reads drained
    if (k < 31) {
      const short* ap = asrc + (k + 1) * 32;
      const short* bp = bsrc + (k + 1) * 32;
      gl_lds16(ap, &As[1 - cur][wave * 512]);
      gl_lds16(bp, &Bs[1 - cur][wave * 512]);
      gl_lds16(bp + 64 * 1024, &Bs[1 - cur][wave * 512 + 2048]);
    }
    bf16x8 af[2], bfr[4];
#pragma unroll
    for (int i = 0; i < 2; ++i)
      af[i] = *(const bf16x8*)&As[cur][(wm + 16 * i + l15) * 32 + quad * 8];
#pragma unroll
    for (int j = 0; j < 4; ++j)
      bfr[j] = *(const bf16x8*)&Bs[cur][(wn + 16 * j + l15) * 32 + quad * 8];
#pragma unroll
    for (int i = 0; i < 2; ++i)
#pragma unroll
      for (int j = 0; j < 4; ++j) acc[i][j] = mfma16(af[i], bfr[j], acc[i][j]);
  }
#pragma unroll
  for (int j = 0; j < 4; ++j) {
    int col = n0 + wn + 16 * j + l15;
    int reg = col >> 6;  // head-slot 0..39 (uniform across the 16 lanes)
    int d = col & 63;
    if (reg < 16) {  // q: pre-scale by 0.125*log2e (softmax fold)
#pragma unroll
      for (int i = 0; i < 2; ++i)
#pragma unroll
        for (int r = 0; r < 4; ++r) {
          int row = m0 + wm + 16 * i + quad * 4 + r;
          int b = row >> 10, tok = row & 1023;
          ((unsigned short*)qc)[((size_t)((b * 16 + reg) * 1024 + tok)) * 64 + d] =
              f2b(acc[i][j][r] * 0.18033688f);
        }
    } else if (reg < 32) {  // gate (+bias)
      float bv = bias[col];
#pragma unroll
      for (int i = 0; i < 2; ++i)
#pragma unroll
        for (int r = 0; r < 4; ++r) {
          int row = m0 + wm + 16 * i + quad * 4 + r;
          int b = row >> 10, tok = row & 1023;
          ((unsigned short*)gc)[((size_t)((b * 16 + reg - 16) * 1024 + tok)) * 64 + d] =
              f2b(acc[i][j][r] + bv);
        }
    } else if (reg < 36) {  // K fragment-packed
      int kvh = reg - 32;
      int dh = d >> 5, dq = (d >> 3) & 3, di = d & 7;
#pragma unroll
      for (int i = 0; i < 2; ++i)
#pragma unroll
        for (int r = 0; r < 4; ++r) {
          int row = m0 + wm + 16 * i + quad * 4 + r;
          int b = row >> 10, tok = row & 1023;
          int kt = tok >> 6, kh = (tok >> 5) & 1, k32 = tok & 31;
          int ksub = k32 >> 4, kl = k32 & 15;
          size_t koff = (size_t)(b * 4 + kvh) * 65536 +
                        (size_t)((kt * 2 + kh) * 2048 + (ksub * 2 + dh) * 512 +
                                 (dq * 16 + kl) * 8 + di);
          ((unsigned short*)kc)[koff] = f2b(acc[i][j][r]);
        }
    } else {  // V fragment-packed (4 consecutive r -> one ushort4)
      int kvh = reg - 36;
      int dt = d >> 4, dl = d & 15;
#pragma unroll
      for (int i = 0; i < 2; ++i) {
        int row0 = m0 + wm + 16 * i + quad * 4;
        int b = row0 >> 10, tok0 = row0 & 1023;
        int kt = tok0 >> 6, kh = (tok0 >> 5) & 1, isub = (tok0 >> 4) & 1;
        size_t voff = (size_t)(b * 4 + kvh) * 65536 +
                      (size_t)((kt * 2 + kh) * 2048 + (isub * 2 + (dt >> 1)) * 512 +
                               (quad * 16 + dl) * 8 + (dt & 1) * 4);
        ushort4 o;
        o.x = f2b(acc[i][j][0]);
        o.y = f2b(acc[i][j][1]);
        o.z = f2b(acc[i][j][2]);
        o.w = f2b(acc[i][j][3]);
        *(ushort4*)&((unsigned short*)vt)[voff] = o;
      }
    }
  }
}

// ---------------------------------------------------------------------------
// Output-projection GEMM (r7-proven): 64x64 tile, grid 16x64 = 1024 blocks,
// BK=32, double-buffered gl_lds, 4 waves = 2x2 of (32m x 32n).
// ---------------------------------------------------------------------------
__global__ __launch_bounds__(256, 4) void gemm_out(
    const short* __restrict__ A, const short* __restrict__ WT,
    float* __restrict__ Cout) {
  __shared__ short As[2][64 * 32];
  __shared__ short Bs[2][64 * 32];
  const int tid = threadIdx.x;
  const int wave = tid >> 6, lane = tid & 63, l15 = lane & 15, quad = lane >> 4;
  const int m0 = blockIdx.y * 64, n0 = blockIdx.x * 64;
  const int wm = (wave & 1) * 32, wn = (wave >> 1) * 32;
  const int arow = tid >> 2, ac = (tid & 3) * 8;
  const short* asrc = A + (size_t)(m0 + arow) * 1024 + ac;
  const short* bsrc = WT + (size_t)(n0 + arow) * 1024 + ac;

  gl_lds16(asrc, &As[0][wave * 512]);
  gl_lds16(bsrc, &Bs[0][wave * 512]);

  f32x4 acc[2][2] = {};
  for (int k = 0; k < 32; ++k) {
    const int cur = k & 1;
    __syncthreads();
    if (k < 31) {
      gl_lds16(asrc + (k + 1) * 32, &As[1 - cur][wave * 512]);
      gl_lds16(bsrc + (k + 1) * 32, &Bs[1 - cur][wave * 512]);
    }
    bf16x8 af[2], bfr[2];
#pragma unroll
    for (int i = 0; i < 2; ++i)
      af[i] = *(const bf16x8*)&As[cur][(wm + 16 * i + l15) * 32 + quad * 8];
#pragma unroll
    for (int j = 0; j < 2; ++j)
      bfr[j] = *(const bf16x8*)&Bs[cur][(wn + 16 * j + l15) * 32 + quad * 8];
#pragma unroll
    for (int i = 0; i < 2; ++i)
#pragma unroll
      for (int j = 0; j < 2; ++j) acc[i][j] = mfma16(af[i], bfr[j], acc[i][j]);
  }
#pragma unroll
  for (int j = 0; j < 2; ++j) {
    int col = n0 + wn + 16 * j + l15;
#pragma unroll
    for (int i = 0; i < 2; ++i) {
#pragma unroll
      for (int r = 0; r < 4; ++r) {
        int row = m0 + wm + 16 * i + quad * 4 + r;
        Cout[(size_t)row * 1024 + col] = acc[i][j][r];
      }
    }
  }
}

// ---------------------------------------------------------------------------
// MFMA flash attention + gate, round 17: r16 structure + FRAGMENT-PACKED K/V.
// r15/r16 post-mortem: 12 scattered loads/wave/kt (8B/lane over 16 rows) were
// TA-address-bound (all pipes idle, time ~ scatter count). Now K/V live in
// packed layouts (written by gemm_proj) where each load is 16B/lane fully
// contiguous (1KB/wave): 8 coalesced loads per wave per kt. Same math, same
// 2x2 wave split, same-register prefetch-1, zero main-loop barriers.
// ---------------------------------------------------------------------------
__global__ __launch_bounds__(256, 4) void attn_mfma14(
    const short* __restrict__ qc, const short* __restrict__ gc,
    const short* __restrict__ kc, const short* __restrict__ vt,
    unsigned short* __restrict__ gated) {
  __shared__ float OA[64 * 33];  // qh=0 partial O^T [d][q&31]
  __shared__ float OB[64 * 33];  // qh=1
  __shared__ float Lpart[4 * 32];
  __shared__ float Lq[64];
  const int tid = threadIdx.x;
  const int w = tid >> 6, lane = tid & 63, l15 = lane & 15, quad = lane >> 4;
  const int qh = w >> 1, kh = w & 1;
  const int qt = blockIdx.x, bh = blockIdx.y, b = bh >> 4, h = bh & 15, kvh = h >> 2;

  // Q B-frags: col q = qt*64 + qh*32 + 16jq + l15, k = d = quad*8+i (+32)
  bf16x8 qf[2][2];
#pragma unroll
  for (int jq = 0; jq < 2; ++jq) {
    const short* qp = qc + ((size_t)((b * 16 + h) * 1024) + qt * 64 + qh * 32 +
                            16 * jq + l15) * 64 + quad * 8;
    qf[jq][0] = *(const bf16x8*)qp;
    qf[jq][1] = *(const bf16x8*)(qp + 32);
  }

  // Packed K/V: per (b,kvh) region 65536 sh; per (kt,kh) 2048 sh; lane-major.
  const short* kp = kc + (size_t)(b * 4 + kvh) * 65536 + kh * 2048 + lane * 8;
  const short* vp = vt + (size_t)(b * 4 + kvh) * 65536 + kh * 2048 + lane * 8;

  f32x4 oacc[2][4] = {};  // [jq][dt]: d = 16dt+4quad+r, q = qh*32+16jq+l15
  float ls[2] = {0.f, 0.f};

  // preload kt=0 (named regs; prefetch rewrites same names)
  bf16x8 kA0 = *(const bf16x8*)(kp);          // keysub0, d 0-31
  bf16x8 kA1 = *(const bf16x8*)(kp + 512);    // keysub0, d 32-63
  bf16x8 kA2 = *(const bf16x8*)(kp + 1024);   // keysub1, d 0-31
  bf16x8 kA3 = *(const bf16x8*)(kp + 1536);   // keysub1, d 32-63
  bf16x8 w0 = *(const bf16x8*)(vp);           // keysub0: dt0|dt1
  bf16x8 w1 = *(const bf16x8*)(vp + 512);     // keysub0: dt2|dt3
  bf16x8 w2 = *(const bf16x8*)(vp + 1024);    // keysub1: dt0|dt1
  bf16x8 w3 = *(const bf16x8*)(vp + 1536);    // keysub1: dt2|dt3

#define EXPPV8(ST, JQ, WA, WB)                                                 \
  {                                                                            \
    float p0 = exp2f((ST)[0]), p1 = exp2f((ST)[1]);                            \
    float p2 = exp2f((ST)[2]), p3 = exp2f((ST)[3]);                            \
    ls[JQ] += (p0 + p1) + (p2 + p3);                                           \
    bf16x4 pbf;                                                                \
    pbf[0] = (short)f2b(p0);                                                   \
    pbf[1] = (short)f2b(p1);                                                   \
    pbf[2] = (short)f2b(p2);                                                   \
    pbf[3] = (short)f2b(p3);                                                   \
    oacc[JQ][0] = mfma16k16(vlo(WA), pbf, oacc[JQ][0]);                        \
    oacc[JQ][1] = mfma16k16(vhi(WA), pbf, oacc[JQ][1]);                        \
    oacc[JQ][2] = mfma16k16(vlo(WB), pbf, oacc[JQ][2]);                        \
    oacc[JQ][3] = mfma16k16(vhi(WB), pbf, oacc[JQ][3]);                        \
  }

  for (int kt = 0; kt < 16; ++kt) {
    const short* kn = kp + 4096;  // K(kt+1)
    const short* vn = vp + 4096;  // V(kt+1)
    // ---- S keysub0 (kA0/kA1 last use), both jq
    f32x4 s00 = mfma16(kA0, qf[0][0], (f32x4){0.f, 0.f, 0.f, 0.f});
    s00 = mfma16(kA1, qf[0][1], s00);
    f32x4 s10 = mfma16(kA0, qf[1][0], (f32x4){0.f, 0.f, 0.f, 0.f});
    s10 = mfma16(kA1, qf[1][1], s10);
    if (kt < 15) {
      kA0 = *(const bf16x8*)(kn);
      kA1 = *(const bf16x8*)(kn + 512);
    }
    EXPPV8(s00, 0, w0, w1);
    EXPPV8(s10, 1, w0, w1);
    // ---- S keysub1 (kA2/kA3 last use)
    f32x4 s01 = mfma16(kA2, qf[0][0], (f32x4){0.f, 0.f, 0.f, 0.f});
    s01 = mfma16(kA3, qf[0][1], s01);
    f32x4 s11 = mfma16(kA2, qf[1][0], (f32x4){0.f, 0.f, 0.f, 0.f});
    s11 = mfma16(kA3, qf[1][1], s11);
    if (kt < 15) {
      kA2 = *(const bf16x8*)(kn + 1024);
      kA3 = *(const bf16x8*)(kn + 1536);
    }
    EXPPV8(s01, 0, w2, w3);
    EXPPV8(s11, 1, w2, w3);
    if (kt < 15) {  // V(kt+1): w regs dead after the PV above
      w0 = *(const bf16x8*)(vn);
      w1 = *(const bf16x8*)(vn + 512);
      w2 = *(const bf16x8*)(vn + 1024);
      w3 = *(const bf16x8*)(vn + 1536);
    }
    kp = kn;
    vp = vn;
  }
#undef EXPPV8

  // l reduction: quad-reduce in-wave (sum over this wave's 512 keys per q)
#pragma unroll
  for (int jq = 0; jq < 2; ++jq) {
    ls[jq] += __shfl_xor(ls[jq], 16);
    ls[jq] += __shfl_xor(ls[jq], 32);
  }
  if (quad == 0) {
#pragma unroll
    for (int jq = 0; jq < 2; ++jq) Lpart[w * 32 + 16 * jq + l15] = ls[jq];
  }

  // cross-wave O reduction: kh=0 waves write their qh buffer; kh=1 waves add.
  float* Ob = qh ? OB : OA;
  if (kh == 0) {
#pragma unroll
    for (int jq = 0; jq < 2; ++jq)
#pragma unroll
      for (int dt = 0; dt < 4; ++dt)
#pragma unroll
        for (int r = 0; r < 4; ++r)
          Ob[(16 * dt + 4 * quad + r) * 33 + 16 * jq + l15] = oacc[jq][dt][r];
  }
  __syncthreads();
  if (kh == 1) {
#pragma unroll
    for (int jq = 0; jq < 2; ++jq)
#pragma unroll
      for (int dt = 0; dt < 4; ++dt)
#pragma unroll
        for (int r = 0; r < 4; ++r)
          Ob[(16 * dt + 4 * quad + r) * 33 + 16 * jq + l15] += oacc[jq][dt][r];
  }
  if (tid < 64) {
    int ql = tid & 31, qh2 = tid >> 5;
    Lq[tid] = Lpart[qh2 * 64 + ql] + Lpart[qh2 * 64 + 32 + ql];
  }
  __syncthreads();

  // epilogue: O rows q = 16jq+4quad+r (jq 0..3), cols d = 16w+l15
  const int d = 16 * w + l15;
#pragma unroll
  for (int jq = 0; jq < 4; ++jq) {
    const float* Osrc = (jq < 2) ? OA : OB;
#pragma unroll
    for (int r = 0; r < 4; ++r) {
      int qloc = 16 * jq + 4 * quad + r;
      float ov = Osrc[d * 33 + (qloc & 31)];
      float lv = Lq[qloc];
      float gv = b2f(((const unsigned short*)gc)[
          ((size_t)((b * 16 + h) * 1024) + qt * 64 + qloc) * 64 + d]);
      size_t row = (size_t)(b * NN + qt * 64 + qloc);
      gated[row * 1024 + h * 64 + d] = f2b(ov / lv * gv);
    }
  }
}

// ---------------------------------------------------------------------------
extern "C" void kernel_launch(void* const* d_in, const int* in_sizes, int n_in,
                              void* d_out, int out_size, void* d_ws,
                              size_t ws_size, hipStream_t stream) {
  const float* x = (const float*)d_in[0];
  const float* Wq = (const float*)d_in[1];
  const float* Wkv = (const float*)d_in[2];
  const float* Wg = (const float*)d_in[3];
  const float* bg = (const float*)d_in[4];
  const float* Wo = (const float*)d_in[5];
  float* out = (float*)d_out;

  // ws layout (short elems): ~36.6 MB total
  short* ws = (short*)d_ws;
  short* xb = ws;                     // 4.19M (x bf16; later aliased as gated)
  short* WcT = xb + 4194304;          // 2.62M (W^T combined: q|g|kv rows)
  short* WoT = WcT + 2621440;         // 1.05M
  short* qc = WoT + 1048576;          // 4.19M  q[b,h,tok,d]
  short* gc = qc + 4194304;           // 4.19M  gate[b,h,tok,d]
  short* kc = gc + 4194304;           // 1.05M  K fragment-packed
  short* vtw = kc + 1048576;          // 1.05M  V fragment-packed
  float* bias_f32 = (float*)(vtw + 1048576);  // 2560 f32

  dim3 blk(256);
  // weight transposes + bias + x-convert, one dispatch
  transpose_all<<<dim3(16, 16, 6), blk, 0, stream>>>(Wq, Wkv, Wg, Wo, bg, x,
                                                     WcT, WoT, bias_f32, xb);
  // fused q|gate|kv projection (outputs diverted to packed layouts)
  gemm_proj<<<dim3(20, 64), blk, 0, stream>>>(xb, WcT, bias_f32, qc, gc, kc, vtw);
  // attention + gate -> gated (aliases xb; xb no longer needed)
  attn_mfma14<<<dim3(16, 64), blk, 0, stream>>>(qc, gc, kc, vtw, (unsigned short*)xb);
  // output projection
  gemm_out<<<dim3(16, 64), blk, 0, stream>>>(xb, WoT, out);
}

// Round 9
// 166.670 us; speedup vs baseline: 1.7766x; 1.0652x over previous
//
#include <hip/hip_runtime.h>
#include <hip/hip_bf16.h>
#include <stdint.h>

#define BB 4
#define NN 1024
#define DD 1024
#define HH 16
#define HDIM 64
#define KVHH 4
#define MM (BB * NN)  // 4096 token rows

typedef __hip_bfloat16 bf16;
typedef __attribute__((ext_vector_type(8))) short bf16x8;  // 8 bf16 = 4 VGPR
typedef __attribute__((ext_vector_type(4))) short bf16x4;  // 4 bf16 = 2 VGPR
typedef __attribute__((ext_vector_type(4))) float f32x4;

__device__ __forceinline__ float b2f(unsigned short u) {
  return __uint_as_float(((unsigned)u) << 16);
}
__device__ __forceinline__ unsigned short f2b(float x) {
  bf16 h = __float2bfloat16(x);
  unsigned short u;
  __builtin_memcpy(&u, &h, 2);
  return u;
}
__device__ __forceinline__ f32x4 mfma16(bf16x8 a, bf16x8 b, f32x4 c) {
  return __builtin_amdgcn_mfma_f32_16x16x32_bf16(a, b, c, 0, 0, 0);
}
// K=16 MFMA: B-fragment layout (col=l15, k=quad*4+i) matches the K=32 MFMA's
// C layout (col=l15, row=quad*4+r) -> S output feeds PV directly, in-register.
// (Correctness HW-verified r12-r17: absmax identical across all rounds.)
__device__ __forceinline__ f32x4 mfma16k16(bf16x4 a, bf16x4 b, f32x4 c) {
#if __has_builtin(__builtin_amdgcn_mfma_f32_16x16x16bf16_1k)
  return __builtin_amdgcn_mfma_f32_16x16x16bf16_1k(a, b, c, 0, 0, 0);
#else
  asm("s_nop 1\n\tv_mfma_f32_16x16x16_bf16 %0, %1, %2, %0"
      : "+v"(c)
      : "v"(a), "v"(b));
  return c;
#endif
}
__device__ __forceinline__ bf16x4 vlo(bf16x8 v) {
  return __builtin_shufflevector(v, v, 0, 1, 2, 3);
}
__device__ __forceinline__ bf16x4 vhi(bf16x8 v) {
  return __builtin_shufflevector(v, v, 4, 5, 6, 7);
}
__device__ __forceinline__ void gl_lds16(const short* g, short* l) {
  __builtin_amdgcn_global_load_lds(
      (const __attribute__((address_space(1))) unsigned*)g,
      (__attribute__((address_space(3))) unsigned*)l, 16, 0, 0);
}

// ---------------------------------------------------------------------------
// z=0..3: weight transposes W (K x N fp32) -> WT (N x K bf16), 64x64 tiles.
// z=4: combined bias build. z=5: x fp32 -> bf16 convert.
// ---------------------------------------------------------------------------
__global__ __launch_bounds__(256) void transpose_all(
    const float* __restrict__ Wq, const float* __restrict__ Wkv,
    const float* __restrict__ Wg, const float* __restrict__ Wo,
    const float* __restrict__ bg, const float* __restrict__ x,
    short* __restrict__ WcT, short* __restrict__ WoT,
    float* __restrict__ bias, short* __restrict__ xb) {
  const int z = blockIdx.z;
  if (z == 4) {  // combined bias: [0,1024)=0, [1024,2048)=bg, [2048,2560)=0
    if (blockIdx.y == 0 && blockIdx.x < 10) {
      int i = blockIdx.x * 256 + threadIdx.x;
      if (i < 2560) bias[i] = (i >= 1024 && i < 2048) ? bg[i - 1024] : 0.f;
    }
    return;
  }
  if (z == 5) {  // x convert: 256 blocks x 256 threads x 16 float4
    int base = (blockIdx.y * 16 + blockIdx.x) * 256 + threadIdx.x;
#pragma unroll
    for (int it = 0; it < 16; ++it) {
      int i = base + it * 65536;
      float4 v = *(const float4*)&x[(size_t)i * 4];
      ushort4 o;
      o.x = f2b(v.x); o.y = f2b(v.y); o.z = f2b(v.z); o.w = f2b(v.w);
      *(ushort4*)&xb[(size_t)i * 4] = o;
    }
    return;
  }
  const float* W;
  short* WT;
  int N = 1024;
  const int K = 1024;
  if (z == 0) { W = Wq; WT = WcT; }
  else if (z == 1) { W = Wg; WT = WcT + 1048576; }
  else if (z == 2) {
    W = Wkv; WT = WcT + 2097152; N = 512;
    if (blockIdx.x >= 8) return;  // uniform early-out, before any sync
  } else { W = Wo; WT = WoT; }

  __shared__ short T[64 * 68];
  const int tid = threadIdx.x;
  const int n0 = blockIdx.x * 64, k0 = blockIdx.y * 64;
  {
    int i0 = tid >> 4, j4 = (tid & 15) * 4;
#pragma unroll
    for (int ii = 0; ii < 4; ++ii) {
      int i = i0 + 16 * ii;
      float4 w = *(const float4*)&W[(size_t)(k0 + i) * N + n0 + j4];
      ushort4 o;
      o.x = f2b(w.x); o.y = f2b(w.y); o.z = f2b(w.z); o.w = f2b(w.w);
      *(ushort4*)&T[i * 68 + j4] = o;
    }
  }
  __syncthreads();
  {
    int n = tid >> 2, k16 = (tid & 3) * 16;
    short tmp[16];
#pragma unroll
    for (int kk = 0; kk < 16; ++kk) tmp[kk] = T[(k16 + kk) * 68 + n];
    short* dst = WT + (size_t)(n0 + n) * K + k0 + k16;
#pragma unroll
    for (int s = 0; s < 16; s += 4) *(ushort4*)&dst[s] = *(const ushort4*)&tmp[s];
  }
}

// ---------------------------------------------------------------------------
// Fused projection GEMM, round 19: 128x128 tile (r18 retry; r18's NaN was an
// LDS offset bug — rows 64..127 of a [128][32] tile start at 64*32=2048, NOT
// 4096 which is the other dbuf half / past the array). Grid 20x32, 4 waves =
// 2x2 of (64m x 64n), acc[4][4]=64 AGPR, BK=32, dbuf gl_lds (4/thread/step).
// __launch_bounds__(256,3): unified cap ~170. Epilogue: reg wave-uniform.
// K/V written in the fragment-packed layouts attn_mfma14 consumes (r17).
// ---------------------------------------------------------------------------
__global__ __launch_bounds__(256, 3) void gemm_proj(
    const short* __restrict__ A, const short* __restrict__ WT,
    const float* __restrict__ bias, short* __restrict__ qc,
    short* __restrict__ gc, short* __restrict__ kc, short* __restrict__ vt) {
  __shared__ short As[2][128 * 32];
  __shared__ short Bs[2][128 * 32];
  const int tid = threadIdx.x;
  const int wave = tid >> 6, lane = tid & 63, l15 = lane & 15, quad = lane >> 4;
  const int m0 = blockIdx.y * 128, n0 = blockIdx.x * 128;
  const int wm = (wave & 1) * 64, wn = (wave >> 1) * 64;
  const int arow = tid >> 2, ac = (tid & 3) * 8;
  const short* asrc = A + (size_t)(m0 + arow) * 1024 + ac;
  const short* bsrc = WT + (size_t)(n0 + arow) * 1024 + ac;

  gl_lds16(asrc, &As[0][wave * 512]);
  gl_lds16(asrc + 64 * 1024, &As[0][2048 + wave * 512]);
  gl_lds16(bsrc, &Bs[0][wave * 512]);
  gl_lds16(bsrc + 64 * 1024, &Bs[0][2048 + wave * 512]);

  f32x4 acc[4][4] = {};
  for (int k = 0; k < 32; ++k) {
    const int cur = k & 1;
    __syncthreads();  // stage(k) landed; iter k-1 LDS reads drained
    if (k < 31) {
      const short* ap = asrc + (k + 1) * 32;
      const short* bp = bsrc + (k + 1) * 32;
      gl_lds16(ap, &As[1 - cur][wave * 512]);
      gl_lds16(ap + 64 * 1024, &As[1 - cur][2048 + wave * 512]);
      gl_lds16(bp, &Bs[1 - cur][wave * 512]);
      gl_lds16(bp + 64 * 1024, &Bs[1 - cur][2048 + wave * 512]);
    }
    bf16x8 af[4], bfr[4];
#pragma unroll
    for (int i = 0; i < 4; ++i)
      af[i] = *(const bf16x8*)&As[cur][(wm + 16 * i + l15) * 32 + quad * 8];
#pragma unroll
    for (int j = 0; j < 4; ++j)
      bfr[j] = *(const bf16x8*)&Bs[cur][(wn + 16 * j + l15) * 32 + quad * 8];
#pragma unroll
    for (int i = 0; i < 4; ++i)
#pragma unroll
      for (int j = 0; j < 4; ++j) acc[i][j] = mfma16(af[i], bfr[j], acc[i][j]);
  }

  const int reg = (n0 + wn) >> 6;  // head-slot 0..39, WAVE-uniform
  if (reg < 16) {  // q: pre-scale by 0.125*log2e (softmax fold)
#pragma unroll
    for (int j = 0; j < 4; ++j) {
      int d = 16 * j + l15;
#pragma unroll
      for (int i = 0; i < 4; ++i)
#pragma unroll
        for (int r = 0; r < 4; ++r) {
          int row = m0 + wm + 16 * i + quad * 4 + r;
          int b = row >> 10, tok = row & 1023;
          ((unsigned short*)qc)[((size_t)((b * 16 + reg) * 1024 + tok)) * 64 + d] =
              f2b(acc[i][j][r] * 0.18033688f);
        }
    }
  } else if (reg < 32) {  // gate (+bias)
#pragma unroll
    for (int j = 0; j < 4; ++j) {
      int d = 16 * j + l15;
      float bv = bias[n0 + wn + d];
#pragma unroll
      for (int i = 0; i < 4; ++i)
#pragma unroll
        for (int r = 0; r < 4; ++r) {
          int row = m0 + wm + 16 * i + quad * 4 + r;
          int b = row >> 10, tok = row & 1023;
          ((unsigned short*)gc)[((size_t)((b * 16 + reg - 16) * 1024 + tok)) * 64 + d] =
              f2b(acc[i][j][r] + bv);
        }
    }
  } else if (reg < 36) {  // K fragment-packed
    int kvh = reg - 32;
#pragma unroll
    for (int j = 0; j < 4; ++j) {
      int d = 16 * j + l15;
      int dh = d >> 5, dq = (d >> 3) & 3, di = d & 7;
#pragma unroll
      for (int i = 0; i < 4; ++i)
#pragma unroll
        for (int r = 0; r < 4; ++r) {
          int row = m0 + wm + 16 * i + quad * 4 + r;
          int b = row >> 10, tok = row & 1023;
          int kt = tok >> 6, kh = (tok >> 5) & 1, k32 = tok & 31;
          int ksub = k32 >> 4, kl = k32 & 15;
          size_t koff = (size_t)(b * 4 + kvh) * 65536 +
                        (size_t)((kt * 2 + kh) * 2048 + (ksub * 2 + dh) * 512 +
                                 (dq * 16 + kl) * 8 + di);
          ((unsigned short*)kc)[koff] = f2b(acc[i][j][r]);
        }
    }
  } else {  // V fragment-packed (4 consecutive r -> one ushort4)
    int kvh = reg - 36;
#pragma unroll
    for (int j = 0; j < 4; ++j) {
      int dt = j;  // d = 16j + l15 -> dt = j, dl = l15
#pragma unroll
      for (int i = 0; i < 4; ++i) {
        int row0 = m0 + wm + 16 * i + quad * 4;
        int b = row0 >> 10, tok0 = row0 & 1023;
        int kt = tok0 >> 6, kh = (tok0 >> 5) & 1, isub = (tok0 >> 4) & 1;
        size_t voff = (size_t)(b * 4 + kvh) * 65536 +
                      (size_t)((kt * 2 + kh) * 2048 + (isub * 2 + (dt >> 1)) * 512 +
                               (quad * 16 + l15) * 8 + (dt & 1) * 4);
        ushort4 o;
        o.x = f2b(acc[i][j][0]);
        o.y = f2b(acc[i][j][1]);
        o.z = f2b(acc[i][j][2]);
        o.w = f2b(acc[i][j][3]);
        *(ushort4*)&((unsigned short*)vt)[voff] = o;
      }
    }
  }
}

// ---------------------------------------------------------------------------
// Output-projection GEMM, round 19: 128x64 tile (r18 retry, LDS offset fixed:
// A rows 64..127 live at 64*32=2048 within the [128][32] tile). Grid 16x32 =
// 512 blocks, 4 waves = 2x2 of (64m x 32n), acc[4][2]=32 AGPR fits (256,4).
// ---------------------------------------------------------------------------
__global__ __launch_bounds__(256, 4) void gemm_out(
    const short* __restrict__ A, const short* __restrict__ WT,
    float* __restrict__ Cout) {
  __shared__ short As[2][128 * 32];
  __shared__ short Bs[2][64 * 32];
  const int tid = threadIdx.x;
  const int wave = tid >> 6, lane = tid & 63, l15 = lane & 15, quad = lane >> 4;
  const int m0 = blockIdx.y * 128, n0 = blockIdx.x * 64;
  const int wm = (wave & 1) * 64, wn = (wave >> 1) * 32;
  const int arow = tid >> 2, ac = (tid & 3) * 8;
  const short* asrc = A + (size_t)(m0 + arow) * 1024 + ac;
  const short* bsrc = WT + (size_t)(n0 + arow) * 1024 + ac;

  gl_lds16(asrc, &As[0][wave * 512]);
  gl_lds16(asrc + 64 * 1024, &As[0][2048 + wave * 512]);
  gl_lds16(bsrc, &Bs[0][wave * 512]);

  f32x4 acc[4][2] = {};
  for (int k = 0; k < 32; ++k) {
    const int cur = k & 1;
    __syncthreads();
    if (k < 31) {
      const short* ap = asrc + (k + 1) * 32;
      gl_lds16(ap, &As[1 - cur][wave * 512]);
      gl_lds16(ap + 64 * 1024, &As[1 - cur][2048 + wave * 512]);
      gl_lds16(bsrc + (k + 1) * 32, &Bs[1 - cur][wave * 512]);
    }
    bf16x8 af[4], bfr[2];
#pragma unroll
    for (int i = 0; i < 4; ++i)
      af[i] = *(const bf16x8*)&As[cur][(wm + 16 * i + l15) * 32 + quad * 8];
#pragma unroll
    for (int j = 0; j < 2; ++j)
      bfr[j] = *(const bf16x8*)&Bs[cur][(wn + 16 * j + l15) * 32 + quad * 8];
#pragma unroll
    for (int i = 0; i < 4; ++i)
#pragma unroll
      for (int j = 0; j < 2; ++j) acc[i][j] = mfma16(af[i], bfr[j], acc[i][j]);
  }
#pragma unroll
  for (int j = 0; j < 2; ++j) {
    int col = n0 + wn + 16 * j + l15;
#pragma unroll
    for (int i = 0; i < 4; ++i) {
#pragma unroll
      for (int r = 0; r < 4; ++r) {
        int row = m0 + wm + 16 * i + quad * 4 + r;
        Cout[(size_t)row * 1024 + col] = acc[i][j][r];
      }
    }
  }
}

// ---------------------------------------------------------------------------
// MFMA flash attention + gate (r17-proven): fragment-packed K/V, 2x2 wave
// split, same-register prefetch-1, zero main-loop barriers. UNCHANGED.
// ---------------------------------------------------------------------------
__global__ __launch_bounds__(256, 4) void attn_mfma14(
    const short* __restrict__ qc, const short* __restrict__ gc,
    const short* __restrict__ kc, const short* __restrict__ vt,
    unsigned short* __restrict__ gated) {
  __shared__ float OA[64 * 33];  // qh=0 partial O^T [d][q&31]
  __shared__ float OB[64 * 33];  // qh=1
  __shared__ float Lpart[4 * 32];
  __shared__ float Lq[64];
  const int tid = threadIdx.x;
  const int w = tid >> 6, lane = tid & 63, l15 = lane & 15, quad = lane >> 4;
  const int qh = w >> 1, kh = w & 1;
  const int qt = blockIdx.x, bh = blockIdx.y, b = bh >> 4, h = bh & 15, kvh = h >> 2;

  // Q B-frags: col q = qt*64 + qh*32 + 16jq + l15, k = d = quad*8+i (+32)
  bf16x8 qf[2][2];
#pragma unroll
  for (int jq = 0; jq < 2; ++jq) {
    const short* qp = qc + ((size_t)((b * 16 + h) * 1024) + qt * 64 + qh * 32 +
                            16 * jq + l15) * 64 + quad * 8;
    qf[jq][0] = *(const bf16x8*)qp;
    qf[jq][1] = *(const bf16x8*)(qp + 32);
  }

  // Packed K/V: per (b,kvh) region 65536 sh; per (kt,kh) 2048 sh; lane-major.
  const short* kp = kc + (size_t)(b * 4 + kvh) * 65536 + kh * 2048 + lane * 8;
  const short* vp = vt + (size_t)(b * 4 + kvh) * 65536 + kh * 2048 + lane * 8;

  f32x4 oacc[2][4] = {};  // [jq][dt]: d = 16dt+4quad+r, q = qh*32+16jq+l15
  float ls[2] = {0.f, 0.f};

  // preload kt=0 (named regs; prefetch rewrites same names)
  bf16x8 kA0 = *(const bf16x8*)(kp);          // keysub0, d 0-31
  bf16x8 kA1 = *(const bf16x8*)(kp + 512);    // keysub0, d 32-63
  bf16x8 kA2 = *(const bf16x8*)(kp + 1024);   // keysub1, d 0-31
  bf16x8 kA3 = *(const bf16x8*)(kp + 1536);   // keysub1, d 32-63
  bf16x8 w0 = *(const bf16x8*)(vp);           // keysub0: dt0|dt1
  bf16x8 w1 = *(const bf16x8*)(vp + 512);     // keysub0: dt2|dt3
  bf16x8 w2 = *(const bf16x8*)(vp + 1024);    // keysub1: dt0|dt1
  bf16x8 w3 = *(const bf16x8*)(vp + 1536);    // keysub1: dt2|dt3

#define EXPPV8(ST, JQ, WA, WB)                                                 \
  {                                                                            \
    float p0 = exp2f((ST)[0]), p1 = exp2f((ST)[1]);                            \
    float p2 = exp2f((ST)[2]), p3 = exp2f((ST)[3]);                            \
    ls[JQ] += (p0 + p1) + (p2 + p3);                                           \
    bf16x4 pbf;                                                                \
    pbf[0] = (short)f2b(p0);                                                   \
    pbf[1] = (short)f2b(p1);                                                   \
    pbf[2] = (short)f2b(p2);                                                   \
    pbf[3] = (short)f2b(p3);                                                   \
    oacc[JQ][0] = mfma16k16(vlo(WA), pbf, oacc[JQ][0]);                        \
    oacc[JQ][1] = mfma16k16(vhi(WA), pbf, oacc[JQ][1]);                        \
    oacc[JQ][2] = mfma16k16(vlo(WB), pbf, oacc[JQ][2]);                        \
    oacc[JQ][3] = mfma16k16(vhi(WB), pbf, oacc[JQ][3]);                        \
  }

  for (int kt = 0; kt < 16; ++kt) {
    const short* kn = kp + 4096;  // K(kt+1)
    const short* vn = vp + 4096;  // V(kt+1)
    // ---- S keysub0 (kA0/kA1 last use), both jq
    f32x4 s00 = mfma16(kA0, qf[0][0], (f32x4){0.f, 0.f, 0.f, 0.f});
    s00 = mfma16(kA1, qf[0][1], s00);
    f32x4 s10 = mfma16(kA0, qf[1][0], (f32x4){0.f, 0.f, 0.f, 0.f});
    s10 = mfma16(kA1, qf[1][1], s10);
    if (kt < 15) {
      kA0 = *(const bf16x8*)(kn);
      kA1 = *(const bf16x8*)(kn + 512);
    }
    EXPPV8(s00, 0, w0, w1);
    EXPPV8(s10, 1, w0, w1);
    // ---- S keysub1 (kA2/kA3 last use)
    f32x4 s01 = mfma16(kA2, qf[0][0], (f32x4){0.f, 0.f, 0.f, 0.f});
    s01 = mfma16(kA3, qf[0][1], s01);
    f32x4 s11 = mfma16(kA2, qf[1][0], (f32x4){0.f, 0.f, 0.f, 0.f});
    s11 = mfma16(kA3, qf[1][1], s11);
    if (kt < 15) {
      kA2 = *(const bf16x8*)(kn + 1024);
      kA3 = *(const bf16x8*)(kn + 1536);
    }
    EXPPV8(s01, 0, w2, w3);
    EXPPV8(s11, 1, w2, w3);
    if (kt < 15) {  // V(kt+1): w regs dead after the PV above
      w0 = *(const bf16x8*)(vn);
      w1 = *(const bf16x8*)(vn + 512);
      w2 = *(const bf16x8*)(vn + 1024);
      w3 = *(const bf16x8*)(vn + 1536);
    }
    kp = kn;
    vp = vn;
  }
#undef EXPPV8

  // l reduction: quad-reduce in-wave (sum over this wave's 512 keys per q)
#pragma unroll
  for (int jq = 0; jq < 2; ++jq) {
    ls[jq] += __shfl_xor(ls[jq], 16);
    ls[jq] += __shfl_xor(ls[jq], 32);
  }
  if (quad == 0) {
#pragma unroll
    for (int jq = 0; jq < 2; ++jq) Lpart[w * 32 + 16 * jq + l15] = ls[jq];
  }

  // cross-wave O reduction: kh=0 waves write their qh buffer; kh=1 waves add.
  float* Ob = qh ? OB : OA;
  if (kh == 0) {
#pragma unroll
    for (int jq = 0; jq < 2; ++jq)
#pragma unroll
      for (int dt = 0; dt < 4; ++dt)
#pragma unroll
        for (int r = 0; r < 4; ++r)
          Ob[(16 * dt + 4 * quad + r) * 33 + 16 * jq + l15] = oacc[jq][dt][r];
  }
  __syncthreads();
  if (kh == 1) {
#pragma unroll
    for (int jq = 0; jq < 2; ++jq)
#pragma unroll
      for (int dt = 0; dt < 4; ++dt)
#pragma unroll
        for (int r = 0; r < 4; ++r)
          Ob[(16 * dt + 4 * quad + r) * 33 + 16 * jq + l15] += oacc[jq][dt][r];
  }
  if (tid < 64) {
    int ql = tid & 31, qh2 = tid >> 5;
    Lq[tid] = Lpart[qh2 * 64 + ql] + Lpart[qh2 * 64 + 32 + ql];
  }
  __syncthreads();

  // epilogue: O rows q = 16jq+4quad+r (jq 0..3), cols d = 16w+l15
  const int d = 16 * w + l15;
#pragma unroll
  for (int jq = 0; jq < 4; ++jq) {
    const float* Osrc = (jq < 2) ? OA : OB;
#pragma unroll
    for (int r = 0; r < 4; ++r) {
      int qloc = 16 * jq + 4 * quad + r;
      float ov = Osrc[d * 33 + (qloc & 31)];
      float lv = Lq[qloc];
      float gv = b2f(((const unsigned short*)gc)[
          ((size_t)((b * 16 + h) * 1024) + qt * 64 + qloc) * 64 + d]);
      size_t row = (size_t)(b * NN + qt * 64 + qloc);
      gated[row * 1024 + h * 64 + d] = f2b(ov / lv * gv);
    }
  }
}

// ---------------------------------------------------------------------------
extern "C" void kernel_launch(void* const* d_in, const int* in_sizes, int n_in,
                              void* d_out, int out_size, void* d_ws,
                              size_t ws_size, hipStream_t stream) {
  const float* x = (const float*)d_in[0];
  const float* Wq = (const float*)d_in[1];
  const float* Wkv = (const float*)d_in[2];
  const float* Wg = (const float*)d_in[3];
  const float* bg = (const float*)d_in[4];
  const float* Wo = (const float*)d_in[5];
  float* out = (float*)d_out;

  // ws layout (short elems): ~36.6 MB total
  short* ws = (short*)d_ws;
  short* xb = ws;                     // 4.19M (x bf16; later aliased as gated)
  short* WcT = xb + 4194304;          // 2.62M (W^T combined: q|g|kv rows)
  short* WoT = WcT + 2621440;         // 1.05M
  short* qc = WoT + 1048576;          // 4.19M  q[b,h,tok,d]
  short* gc = qc + 4194304;           // 4.19M  gate[b,h,tok,d]
  short* kc = gc + 4194304;           // 1.05M  K fragment-packed
  short* vtw = kc + 1048576;          // 1.05M  V fragment-packed
  float* bias_f32 = (float*)(vtw + 1048576);  // 2560 f32

  dim3 blk(256);
  // weight transposes + bias + x-convert, one dispatch
  transpose_all<<<dim3(16, 16, 6), blk, 0, stream>>>(Wq, Wkv, Wg, Wo, bg, x,
                                                     WcT, WoT, bias_f32, xb);
  // fused q|gate|kv projection (outputs diverted to packed layouts)
  gemm_proj<<<dim3(20, 32), blk, 0, stream>>>(xb, WcT, bias_f32, qc, gc, kc, vtw);
  // attention + gate -> gated (aliases xb; xb no longer needed)
  attn_mfma14<<<dim3(16, 64), blk, 0, stream>>>(qc, gc, kc, vtw, (unsigned short*)xb);
  // output projection
  gemm_out<<<dim3(16, 32), blk, 0, stream>>>(xb, WoT, out);
}